// Round 10
// baseline (7139.581 us; speedup 1.0000x reference)
//
#include <hip/hip_runtime.h>
#include <hip/hip_bf16.h>
#include <math.h>

#define SS 2048
#define BB 32
#define SBTOK (SS * BB)   // 65536 tokens
#define NEG (-1e30f)

typedef _Float16 half2_t __attribute__((ext_vector_type(2)));
typedef _Float16 half8_t __attribute__((ext_vector_type(8)));
typedef float f32x4_t __attribute__((ext_vector_type(4)));

#if __has_builtin(__builtin_amdgcn_rcpf)
#define FRCP(x) __builtin_amdgcn_rcpf(x)
#else
#define FRCP(x) (1.f / (x))
#endif

// fast sigmoid / tanh (v_rcp based, ~1 ulp rcp; plenty for 2% tolerance)
__device__ __forceinline__ float fsig(float x) {
  float e = __expf(-x);
  return FRCP(1.f + e);
}
__device__ __forceinline__ float ftanh(float x) {
  float e = __expf(-2.f * fabsf(x));           // in (0,1]
  float r = 1.f - (e + e) * FRCP(1.f + e);     // tanh(|x|)
  return copysignf(r, x);
}
__device__ __forceinline__ float lse3(float x, float y, float z) {
  float mx = fmaxf(fmaxf(x, y), z);
  return mx + __logf(__expf(x - mx) + __expf(y - mx) + __expf(z - mx));
}

// ---------------- K0: zero scratch (state buffers) ----------------
__global__ __launch_bounds__(256) void zero_kernel(float* __restrict__ p, int n) {
  int i = blockIdx.x * 256 + threadIdx.x;
  if (i < n) p[i] = 0.f;
}

// ---------------- K1: char-LSTM features (1 step, h0=c0=0) ----------------
__global__ __launch_bounds__(256) void char_kernel(
    const int* __restrict__ seq, const float* __restrict__ cemb,
    const float* __restrict__ cWih, const float* __restrict__ cb,
    float* __restrict__ char_feat)
{
  int gid = blockIdx.x * 256 + threadIdx.x;
  int token = gid >> 6;          // t*B + b
  int u = gid & 63;
  int dir = u >> 5;
  int j = u & 31;
  int t = token >> 5;            // B = 32
  int b = token & 31;
  int sv = seq[b * SS + t] & 255;
  const float* ce = cemb + sv * 32;
  const float* Wd = cWih + dir * (128 * 32);
  float ai = cb[dir * 128 + j];
  float ag = cb[dir * 128 + 64 + j];
  float ao = cb[dir * 128 + 96 + j];
  #pragma unroll
  for (int k = 0; k < 32; ++k) {
    float cv = ce[k];
    ai = fmaf(cv, Wd[j * 32 + k], ai);
    ag = fmaf(cv, Wd[(64 + j) * 32 + k], ag);
    ao = fmaf(cv, Wd[(96 + j) * 32 + k], ao);
  }
  float c = fsig(ai) * ftanh(ag);
  float h = fsig(ao) * ftanh(c);
  char_feat[(size_t)token * 64 + dir * 32 + j] = h;
}

// ---------------- K2: input projection GEMM (128x64 tile, swizzled LDS) ----------------
#define SWZ(m) ((m) + (((m) >> 4) << 2))
template<int MODE, int D>
__global__ __launch_bounds__(256, 3) void proj_seg(
    const float* __restrict__ Asrc, const int* __restrict__ seq,
    const float* __restrict__ wemb, const float* __restrict__ W,
    const float* __restrict__ bias, float* __restrict__ xg,
    int Tc, int p)
{
  __shared__ float As[32][156];   // [k][swz(m)], m<128 -> idx<=155
  __shared__ float Bs[32][76];    // [k][swz(n)], n<64  -> idx<=75
  int tid = threadIdx.x;
  int tile_m = blockIdx.x * 128;  // over m = s_local*BB + b
  int tile_n = blockIdx.y * 64;   // over 1024 gates
  int dir = tile_n >> 9;
  int tx = tid & 15, ty = tid >> 4;
  float acc[8][4] = {};
  for (int k0 = 0; k0 < D; k0 += 32) {
    #pragma unroll
    for (int l = tid; l < 4096; l += 256) {
      int row = l >> 5, k = l & 31;
      int m = tile_m + row;
      int s_local = m >> 5, b = m & 31;
      int t = dir ? (SS - 1 - p * Tc - s_local) : (p * Tc + s_local);
      int d = k0 + k;
      float av;
      if constexpr (MODE == 0) {
        if (d < 128) {
          int sv = seq[b * SS + t] & 255;
          av = wemb[sv * 128 + d];
        } else {
          av = Asrc[(size_t)(t * BB + b) * 64 + (d - 128)];
        }
      } else {
        av = Asrc[(size_t)(t * BB + b) * 256 + d];
      }
      As[k][SWZ(row)] = av;
    }
    #pragma unroll
    for (int l = tid; l < 2048; l += 256) {
      int row = l >> 5, k = l & 31;
      Bs[k][SWZ(row)] = W[(size_t)(tile_n + row) * D + (k0 + k)];
    }
    __syncthreads();
    int abase = SWZ(ty * 8);
    int bbase = SWZ(tx * 4);
    #pragma unroll
    for (int k = 0; k < 32; ++k) {
      float4 av0 = *(const float4*)&As[k][abase];
      float4 av1 = *(const float4*)&As[k][abase + 4];
      float4 bv = *(const float4*)&Bs[k][bbase];
      float a[8] = {av0.x, av0.y, av0.z, av0.w, av1.x, av1.y, av1.z, av1.w};
      float bq[4] = {bv.x, bv.y, bv.z, bv.w};
      #pragma unroll
      for (int i = 0; i < 8; ++i)
        #pragma unroll
        for (int jj = 0; jj < 4; ++jj)
          acc[i][jj] = fmaf(a[i], bq[jj], acc[i][jj]);
    }
    __syncthreads();
  }
  int nbase = tile_n + tx * 4;
  float4 bb4 = *(const float4*)&bias[nbase];
  #pragma unroll
  for (int i = 0; i < 8; ++i) {
    int m = tile_m + ty * 8 + i;
    int s_local = m >> 5, b = m & 31;
    float4 o;
    o.x = acc[i][0] + bb4.x; o.y = acc[i][1] + bb4.y;
    o.z = acc[i][2] + bb4.z; o.w = acc[i][3] + bb4.w;
    *(float4*)&xg[(((size_t)dir * Tc + s_local) * BB + b) * 512 + (nbase & 511)] = o;
  }
}

// ---------------- K3: LSTM recurrence scan (MFMA, LDS-resident weights) ----------------
// 8 WGs = dir(2) x batch-group(4, 8 batches each). 512 threads = 8 waves.
// Per step: G[8,512] = H[8..16,128] @ Whh^T via mfma_f32_16x16x32_f16,
// G->LDS(f16, padded rows), then all threads do activations (2 elems each).
// Whh lives in LDS as f16 with XOR swizzle ((row&7)<<3 element-XOR) so the
// 16-lane row-strided b128 fragment reads are ~2-way (free) instead of 16-way.
template<int L>
__global__ __launch_bounds__(512, 1) void scan_seg(
    const float* __restrict__ xg,   // [2][Tc][B][512] f32
    const float* __restrict__ Whh,  // [2][512][128] f32
    float* __restrict__ hout,
    float* __restrict__ hstate,     // [2][B][128]
    float* __restrict__ cstate,     // [2][B][128]
    int Tc, int p)
{
  __shared__ alignas(16) _Float16 Wl[65536];  // [512][128] swizzled, 128 KB
  __shared__ alignas(16) _Float16 Hl[2048];   // [16][128] swizzled (rows 8..15 zero)
  __shared__ alignas(16) _Float16 Gl[5120];   // [512][10] (8 batches + pad)
  int tid = threadIdx.x;
  int dir = blockIdx.x >> 2;
  int bg  = blockIdx.x & 3;
  const float* xgd  = xg + (size_t)dir * Tc * BB * 512;
  const float* Wsrc = Whh + (size_t)dir * 65536;

  // one-time: Whh -> LDS f16 (swizzled), H init from hstate
  for (int idx = tid; idx < 65536; idx += 512) {
    int n = idx >> 7;
    Wl[idx ^ ((n & 7) << 3)] = (_Float16)Wsrc[idx];
  }
  for (int idx = tid; idx < 2048; idx += 512) {
    int m = idx >> 7, k = idx & 127;
    float v = (m < 8) ? hstate[((dir * 32 + bg * 8 + m) << 7) + k] : 0.f;
    Hl[idx ^ ((m & 7) << 3)] = (_Float16)v;
  }

  // MFMA-phase roles
  int l = tid & 63, w = tid >> 6;
  int n0 = w << 6;                 // wave owns gates [n0, n0+64)
  int ma = l & 15;
  int koff = (l >> 4) << 3;        // k sub-offset within 32-slice
  // activation-phase roles
  int jj = tid & 127, bq = tid >> 7;
  int bl0 = bq, bl1 = bq + 4;      // local batches (2 per thread)
  int gb0 = bg * 8 + bl0, gb1 = bg * 8 + bl1;
  float c0 = cstate[((dir * 32 + gb0) << 7) + jj];
  float c1 = cstate[((dir * 32 + gb1) << 7) + jj];
  __syncthreads();

  int tbase = dir ? (SS - 1 - p * Tc) : p * Tc;
  int dt = dir ? -1 : 1;

  // depth-2 xg prefetch ring (static indexing only — rule #20)
  float x0[8], x1[8];
  #pragma unroll
  for (int g = 0; g < 4; ++g) {
    x0[g]     = xgd[(size_t)gb0 * 512 + g * 128 + jj];
    x0[4 + g] = xgd[(size_t)gb1 * 512 + g * 128 + jj];
    x1[g]     = xgd[((size_t)BB + gb0) * 512 + g * 128 + jj];
    x1[4 + g] = xgd[((size_t)BB + gb1) * 512 + g * 128 + jj];
  }

  for (int s = 0; s < Tc; ++s) {
    float x2[8];
    if (s + 2 < Tc) {
      #pragma unroll
      for (int g = 0; g < 4; ++g) {
        x2[g]     = xgd[((size_t)(s + 2) * BB + gb0) * 512 + g * 128 + jj];
        x2[4 + g] = xgd[((size_t)(s + 2) * BB + gb1) * 512 + g * 128 + jj];
      }
    } else {
      #pragma unroll
      for (int g = 0; g < 8; ++g) x2[g] = 0.f;
    }

    // ---- MFMA phase: G = H @ Whh^T ----
    half8_t af[4];
    #pragma unroll
    for (int ks = 0; ks < 4; ++ks) {
      int ei = (ma << 7) + ks * 32 + koff;
      af[ks] = *(const half8_t*)&Hl[ei ^ ((ma & 7) << 3)];
    }
    #pragma unroll
    for (int nt = 0; nt < 4; ++nt) {
      int n = n0 + nt * 16 + ma;
      f32x4_t acc = {0.f, 0.f, 0.f, 0.f};
      #pragma unroll
      for (int ks = 0; ks < 4; ++ks) {
        int ei = (n << 7) + ks * 32 + koff;
        half8_t bf = *(const half8_t*)&Wl[ei ^ ((n & 7) << 3)];
        acc = __builtin_amdgcn_mfma_f32_16x16x32_f16(af[ks], bf, acc, 0, 0, 0);
      }
      // D: col = lane&15 (n), row = (lane>>4)*4+reg (batch m); keep m<8
      if (l < 32) {
        int m0 = (l >> 4) << 2;
        int gi = n * 10 + m0;
        half2_t p01, p23;
        p01.x = (_Float16)acc[0]; p01.y = (_Float16)acc[1];
        p23.x = (_Float16)acc[2]; p23.y = (_Float16)acc[3];
        *(half2_t*)&Gl[gi] = p01;
        *(half2_t*)&Gl[gi + 2] = p23;
      }
    }
    __syncthreads();

    // ---- activation phase ----
    float pre0[4], pre1[4];
    #pragma unroll
    for (int g = 0; g < 4; ++g) {
      pre0[g] = x0[g]     + (float)Gl[(g * 128 + jj) * 10 + bl0];
      pre1[g] = x0[4 + g] + (float)Gl[(g * 128 + jj) * 10 + bl1];
    }
    c0 = fsig(pre0[1]) * c0 + fsig(pre0[0]) * ftanh(pre0[2]);
    float h0v = fsig(pre0[3]) * ftanh(c0);
    c1 = fsig(pre1[1]) * c1 + fsig(pre1[0]) * ftanh(pre1[2]);
    float h1v = fsig(pre1[3]) * ftanh(c1);

    Hl[((bl0 << 7) | jj) ^ ((bl0 & 7) << 3)] = (_Float16)h0v;
    Hl[((bl1 << 7) | jj) ^ ((bl1 & 7) << 3)] = (_Float16)h1v;

    if constexpr (L == 0) {
      int t = tbase + dt * s;
      hout[((size_t)t * BB + gb0) * 256 + (dir << 7) + jj] = h0v;
      hout[((size_t)t * BB + gb1) * 256 + (dir << 7) + jj] = h1v;
    } else {
      hout[(((size_t)dir * Tc + s) * BB + gb0) * 128 + jj] = h0v;
      hout[(((size_t)dir * Tc + s) * BB + gb1) * 128 + jj] = h1v;
    }
    __syncthreads();
    #pragma unroll
    for (int g = 0; g < 8; ++g) { x0[g] = x1[g]; x1[g] = x2[g]; }
  }

  // carry state to next chunk
  cstate[((dir * 32 + gb0) << 7) + jj] = c0;
  cstate[((dir * 32 + gb1) << 7) + jj] = c1;
  for (int idx = tid; idx < 1024; idx += 512) {
    int m = idx >> 7, k = idx & 127;
    hstate[((dir * 32 + bg * 8 + m) << 7) + k] = (float)Hl[idx ^ ((m & 7) << 3)];
  }
}

// ---------------- K4: partial emissions from layer-1 h chunk ----------------
__global__ __launch_bounds__(256) void emis_seg(
    const float* __restrict__ h1c, const float* __restrict__ Wtag,
    float* __restrict__ em_part, int Tc, int p)
{
  int wv = blockIdx.x * 4 + (threadIdx.x >> 6);   // over (dir, s, b)
  int lane = threadIdx.x & 63;
  int b = wv & 31;
  int rest = wv >> 5;
  int dir = (rest >= Tc) ? 1 : 0;
  int s = rest - dir * Tc;
  float2 hv = ((const float2*)(h1c + (((size_t)dir * Tc + s) * BB + b) * 128))[lane];
  float pv[3];
  #pragma unroll
  for (int tg = 0; tg < 3; ++tg) {
    float2 wvv = ((const float2*)(Wtag + tg * 256 + dir * 128))[lane];
    pv[tg] = hv.x * wvv.x + hv.y * wvv.y;
  }
  #pragma unroll
  for (int off = 32; off > 0; off >>= 1) {
    pv[0] += __shfl_xor(pv[0], off);
    pv[1] += __shfl_xor(pv[1], off);
    pv[2] += __shfl_xor(pv[2], off);
  }
  if (lane == 0) {
    int t = dir ? (SS - 1 - p * Tc - s) : (p * Tc + s);
    size_t base = ((size_t)dir * SBTOK + (size_t)t * BB + b) * 3;
    em_part[base + 0] = pv[0];
    em_part[base + 1] = pv[1];
    em_part[base + 2] = pv[2];
  }
}

// ---------------- K5a: CRF chunk transfer matrices ----------------
__global__ __launch_bounds__(256) void crf_seg(
    const float* __restrict__ ef, const float* __restrict__ eb,
    const float* __restrict__ btag, const float* __restrict__ masks,
    const float* __restrict__ dummy, const float* __restrict__ tr_,
    float* __restrict__ segM)
{
  int b = blockIdx.x;
  int tid = threadIdx.x;
  int ch = tid >> 4;
  int lane = tid & 63;
  int jj = tid & 15;
  int base = lane & 48;
  int col = (jj < 3) ? jj : 0;
  float T0 = tr_[0 * 3 + col], T1 = tr_[1 * 3 + col], T2 = tr_[2 * 3 + col];
  float btj = btag[col];
  const int* mk = (const int*)masks + (size_t)b * SS;
  int t0 = 1 + ch * 128;
  int len = (ch == 15) ? 127 : 128;
  float S0, S1, S2;
  {
    size_t eo = ((size_t)t0 * BB + b) * 3;
    float e = ef[eo + col] + eb[eo + col] + btj;
    if (mk[t0] != 0) { S0 = T0 + e; S1 = T1 + e; S2 = T2 + e; }
    else { S0 = (col == 0) ? 0.f : NEG; S1 = (col == 1) ? 0.f : NEG; S2 = (col == 2) ? 0.f : NEG; }
  }
  for (int i = 1; i < len; ++i) {
    int t = t0 + i;
    size_t eo = ((size_t)t * BB + b) * 3;
    float e = ef[eo + col] + eb[eo + col] + btj;
    int m = mk[t];
    float M0 = T0 + e, M1 = T1 + e, M2 = T2 + e;
    float r00 = __shfl(S0, base + 0), r01 = __shfl(S0, base + 1), r02 = __shfl(S0, base + 2);
    float r10 = __shfl(S1, base + 0), r11 = __shfl(S1, base + 1), r12 = __shfl(S1, base + 2);
    float r20 = __shfl(S2, base + 0), r21 = __shfl(S2, base + 1), r22 = __shfl(S2, base + 2);
    if (m != 0) {
      S0 = lse3(r00 + M0, r01 + M1, r02 + M2);
      S1 = lse3(r10 + M0, r11 + M1, r12 + M2);
      S2 = lse3(r20 + M0, r21 + M1, r22 + M2);
    }
  }
  if (jj < 3) {
    float* o = segM + ((size_t)b * 16 + ch) * 9;
    o[0 * 3 + jj] = S0;
    o[1 * 3 + jj] = S1;
    o[2 * 3 + jj] = S2;
  }
}

// ---------------- K5b: gold path score (parallel over t) ----------------
__global__ __launch_bounds__(64) void crf_num(
    const float* __restrict__ ef, const float* __restrict__ eb,
    const float* __restrict__ btag, const int* __restrict__ tags,
    const int* __restrict__ masks, const float* __restrict__ st,
    const float* __restrict__ et, const float* __restrict__ tr_,
    float* __restrict__ numb)
{
  int b = blockIdx.x;
  int lane = threadIdx.x;
  float T[9];
  #pragma unroll
  for (int i = 0; i < 9; ++i) T[i] = tr_[i];
  float b0 = btag[0], b1 = btag[1], b2 = btag[2];
  const int* tg = tags + (size_t)b * SS;
  const int* mk = masks + (size_t)b * SS;
  float part = 0.f;
  int cnt = 0;
  for (int t = lane; t < SS; t += 64) {
    int m = mk[t];
    cnt += (m != 0);
    if (t > 0 && m != 0) {
      int ct = tg[t], pv = tg[t - 1];
      size_t eo = ((size_t)t * BB + b) * 3;
      float bc = (ct == 0) ? b0 : ((ct == 1) ? b1 : b2);
      part += T[pv * 3 + ct] + ef[eo + ct] + eb[eo + ct] + bc;
    }
  }
  #pragma unroll
  for (int off = 32; off > 0; off >>= 1) {
    part += __shfl_xor(part, off);
    cnt += __shfl_xor(cnt, off);
  }
  if (lane == 0) {
    int tg0 = tg[0];
    float bc = (tg0 == 0) ? b0 : ((tg0 == 1) ? b1 : b2);
    float num = part + st[tg0] + ef[b * 3 + tg0] + eb[b * 3 + tg0] + bc;
    int last = tg[cnt - 1];
    num += et[last];
    numb[b] = num;
  }
}

// ---------------- K5c: combine chunks, partition, final NLL ----------------
__global__ __launch_bounds__(512) void crf_fin(
    const float* __restrict__ segM, const float* __restrict__ numb,
    const float* __restrict__ ef, const float* __restrict__ eb,
    const float* __restrict__ btag, const float* __restrict__ st,
    const float* __restrict__ et, float* __restrict__ out)
{
  int tid = threadIdx.x;
  int b = tid >> 4;
  int lane = tid & 63;
  int jj = tid & 15;
  int base = lane & 48;
  int col = (jj < 3) ? jj : 0;
  const float* sm = segM + (size_t)b * 16 * 9;
  float S0 = sm[0 * 3 + col], S1 = sm[1 * 3 + col], S2 = sm[2 * 3 + col];
  for (int ch = 1; ch < 16; ++ch) {
    float M0 = sm[ch * 9 + 0 * 3 + col];
    float M1 = sm[ch * 9 + 1 * 3 + col];
    float M2 = sm[ch * 9 + 2 * 3 + col];
    float r00 = __shfl(S0, base + 0), r01 = __shfl(S0, base + 1), r02 = __shfl(S0, base + 2);
    float r10 = __shfl(S1, base + 0), r11 = __shfl(S1, base + 1), r12 = __shfl(S1, base + 2);
    float r20 = __shfl(S2, base + 0), r21 = __shfl(S2, base + 1), r22 = __shfl(S2, base + 2);
    S0 = lse3(r00 + M0, r01 + M1, r02 + M2);
    S1 = lse3(r10 + M0, r11 + M1, r12 + M2);
    S2 = lse3(r20 + M0, r21 + M1, r22 + M2);
  }
  float A0 = st[0] + ef[b * 3 + 0] + eb[b * 3 + 0] + btag[0];
  float A1 = st[1] + ef[b * 3 + 1] + eb[b * 3 + 1] + btag[1];
  float A2 = st[2] + ef[b * 3 + 2] + eb[b * 3 + 2] + btag[2];
  float alpha = lse3(A0 + S0, A1 + S1, A2 + S2);   // column jj
  float v = alpha + et[col];
  float v0 = __shfl(v, base + 0), v1 = __shfl(v, base + 1), v2 = __shfl(v, base + 2);
  float den = lse3(v0, v1, v2);
  __shared__ float rbuf[32];
  if (jj == 0) rbuf[b] = numb[b] - den;
  __syncthreads();
  if (tid == 0) {
    float s = 0.f;
    #pragma unroll
    for (int i = 0; i < 32; ++i) s += rbuf[i];
    out[0] = -s;
  }
}

extern "C" void kernel_launch(void* const* d_in, const int* in_sizes, int n_in,
                              void* d_out, int out_size, void* d_ws, size_t ws_size,
                              hipStream_t stream) {
  const int* seq    = (const int*)d_in[0];
  const int* tags   = (const int*)d_in[1];
  const int* masks  = (const int*)d_in[2];
  const float* wemb = (const float*)d_in[3];
  const float* cemb = (const float*)d_in[4];
  const float* cWih = (const float*)d_in[5];
  const float* cb   = (const float*)d_in[6];
  const float* l0Wih = (const float*)d_in[7];
  const float* l0Whh = (const float*)d_in[8];
  const float* l0b   = (const float*)d_in[9];
  const float* l1Wih = (const float*)d_in[10];
  const float* l1Whh = (const float*)d_in[11];
  const float* l1b   = (const float*)d_in[12];
  const float* Wtag  = (const float*)d_in[13];
  const float* btag  = (const float*)d_in[14];
  const float* st    = (const float*)d_in[15];
  const float* et    = (const float*)d_in[16];
  const float* tr    = (const float*)d_in[17];
  float* outp = (float*)d_out;

  // ---- choose time-chunk Tc so the workspace fits ws_size ----
  const size_t fixed_fl = 4194304ull + 16777216ull + 393216ull + 16384ull + 8192ull;
  int Tc = 64;
  const int cands[6] = {2048, 1024, 512, 256, 128, 64};
  for (int i = 0; i < 6; ++i) {
    size_t need = (fixed_fl + (size_t)cands[i] * 40960ull) * 4ull;
    if (need <= ws_size || i == 5) { Tc = cands[i]; if (need <= ws_size) break; }
  }
  int nphase = SS / Tc;

  float* ws = (float*)d_ws;
  float* char_feat = ws;                              // 4,194,304
  float* xg      = char_feat + 4194304;               // Tc*32768
  float* h0      = xg + (size_t)Tc * 32768;           // 16,777,216
  float* h1c     = h0 + 16777216;                     // Tc*8192
  float* em_part = h1c + (size_t)Tc * 8192;           // 393,216
  float* hstate  = em_part + 393216;                  // 8,192
  float* cstate  = hstate + 8192;                     // 8,192
  float* segM    = cstate + 8192;                     // 4,608
  float* numb    = segM + 4608;                       // 32

  char_kernel<<<SBTOK * 64 / 256, 256, 0, stream>>>(seq, cemb, cWih, cb, char_feat);

  dim3 pg(Tc / 4, 16);
  // ---- layer 0 ----
  zero_kernel<<<64, 256, 0, stream>>>(hstate, 16384);
  for (int p = 0; p < nphase; ++p) {
    proj_seg<0, 192><<<pg, 256, 0, stream>>>(char_feat, seq, wemb, l0Wih, l0b, xg, Tc, p);
    scan_seg<0><<<8, 512, 0, stream>>>(xg, l0Whh, h0, hstate, cstate, Tc, p);
  }
  // ---- layer 1 ----
  zero_kernel<<<64, 256, 0, stream>>>(hstate, 16384);
  for (int p = 0; p < nphase; ++p) {
    proj_seg<1, 256><<<pg, 256, 0, stream>>>(h0, seq, wemb, l1Wih, l1b, xg, Tc, p);
    scan_seg<1><<<8, 512, 0, stream>>>(xg, l1Whh, h1c, hstate, cstate, Tc, p);
    emis_seg<<<Tc * 16, 256, 0, stream>>>(h1c, Wtag, em_part, Tc, p);
  }
  const float* ef = em_part;
  const float* eb = em_part + (size_t)SBTOK * 3;
  crf_seg<<<32, 256, 0, stream>>>(ef, eb, btag, (const float*)masks, nullptr, tr, segM);
  crf_num<<<32, 64, 0, stream>>>(ef, eb, btag, tags, masks, st, et, tr, numb);
  crf_fin<<<1, 512, 0, stream>>>(segM, numb, ef, eb, btag, st, et, outp);
}

// Round 11
// 5150.976 us; speedup vs baseline: 1.3861x; 1.3861x over previous
//
#include <hip/hip_runtime.h>
#include <hip/hip_bf16.h>
#include <math.h>

#define SS 2048
#define BB 32
#define SBTOK (SS * BB)   // 65536 tokens
#define NEG (-1e30f)

typedef _Float16 half2_t __attribute__((ext_vector_type(2)));

#if __has_builtin(__builtin_amdgcn_fdot2)
#define DOT2(a, b, c) __builtin_amdgcn_fdot2((a), (b), (c), false)
#else
#define DOT2(a, b, c) fmaf((float)(a).x, (float)(b).x, fmaf((float)(a).y, (float)(b).y, (c)))
#endif

#if __has_builtin(__builtin_amdgcn_rcpf)
#define FRCP(x) __builtin_amdgcn_rcpf(x)
#else
#define FRCP(x) (1.f / (x))
#endif

__device__ __forceinline__ half2_t f2h2(float f) {
  union { float f; half2_t h; } u; u.f = f; return u.h;
}
__device__ __forceinline__ float h22f(half2_t h) {
  union { half2_t h; float f; } u; u.h = h; return u.f;
}

// fast sigmoid / tanh (v_rcp based, ~1 ulp rcp; plenty for 2% tolerance)
__device__ __forceinline__ float fsig(float x) {
  float e = __expf(-x);
  return FRCP(1.f + e);
}
__device__ __forceinline__ float ftanh(float x) {
  float e = __expf(-2.f * fabsf(x));           // in (0,1]
  float r = 1.f - (e + e) * FRCP(1.f + e);     // tanh(|x|)
  return copysignf(r, x);
}
__device__ __forceinline__ float lse3(float x, float y, float z) {
  float mx = fmaxf(fmaxf(x, y), z);
  return mx + __logf(__expf(x - mx) + __expf(y - mx) + __expf(z - mx));
}

// ---------------- K0: zero scratch (state buffers) ----------------
__global__ __launch_bounds__(256) void zero_kernel(float* __restrict__ p, int n) {
  int i = blockIdx.x * 256 + threadIdx.x;
  if (i < n) p[i] = 0.f;
}

// ---------------- K1: char-LSTM features (1 step, h0=c0=0) ----------------
__global__ __launch_bounds__(256) void char_kernel(
    const int* __restrict__ seq, const float* __restrict__ cemb,
    const float* __restrict__ cWih, const float* __restrict__ cb,
    float* __restrict__ char_feat)
{
  int gid = blockIdx.x * 256 + threadIdx.x;
  int token = gid >> 6;          // t*B + b
  int u = gid & 63;
  int dir = u >> 5;
  int j = u & 31;
  int t = token >> 5;            // B = 32
  int b = token & 31;
  int sv = seq[b * SS + t] & 255;
  const float* ce = cemb + sv * 32;
  const float* Wd = cWih + dir * (128 * 32);
  float ai = cb[dir * 128 + j];
  float ag = cb[dir * 128 + 64 + j];
  float ao = cb[dir * 128 + 96 + j];
  #pragma unroll
  for (int k = 0; k < 32; ++k) {
    float cv = ce[k];
    ai = fmaf(cv, Wd[j * 32 + k], ai);
    ag = fmaf(cv, Wd[(64 + j) * 32 + k], ag);
    ao = fmaf(cv, Wd[(96 + j) * 32 + k], ao);
  }
  float c = fsig(ai) * ftanh(ag);
  float h = fsig(ao) * ftanh(c);
  char_feat[(size_t)token * 64 + dir * 32 + j] = h;
}

// ---------------- K2: input projection GEMM (128x64 tile, round-4 layout) ----------------
template<int MODE, int D>
__global__ __launch_bounds__(256, 3) void proj_seg(
    const float* __restrict__ Asrc, const int* __restrict__ seq,
    const float* __restrict__ wemb, const float* __restrict__ W,
    const float* __restrict__ bias, float* __restrict__ xg,
    int Tc, int p)
{
  __shared__ float As[32][132];   // [k][m]
  __shared__ float Bs[32][68];    // [k][n]
  int tid = threadIdx.x;
  int tile_m = blockIdx.x * 128;  // over m = s_local*BB + b
  int tile_n = blockIdx.y * 64;   // over 1024 gates
  int dir = tile_n >> 9;
  int tx = tid & 15, ty = tid >> 4;
  float acc[8][4] = {};
  for (int k0 = 0; k0 < D; k0 += 32) {
    #pragma unroll
    for (int l = tid; l < 4096; l += 256) {
      int row = l >> 5, k = l & 31;
      int m = tile_m + row;
      int s_local = m >> 5, b = m & 31;
      int t = dir ? (SS - 1 - p * Tc - s_local) : (p * Tc + s_local);
      int d = k0 + k;
      float av;
      if constexpr (MODE == 0) {
        if (d < 128) {
          int sv = seq[b * SS + t] & 255;
          av = wemb[sv * 128 + d];
        } else {
          av = Asrc[(size_t)(t * BB + b) * 64 + (d - 128)];
        }
      } else {
        av = Asrc[(size_t)(t * BB + b) * 256 + d];
      }
      As[k][row] = av;
    }
    #pragma unroll
    for (int l = tid; l < 2048; l += 256) {
      int row = l >> 5, k = l & 31;
      Bs[k][row] = W[(size_t)(tile_n + row) * D + (k0 + k)];
    }
    __syncthreads();
    #pragma unroll
    for (int k = 0; k < 32; ++k) {
      float4 av0 = *(const float4*)&As[k][ty * 8];
      float4 av1 = *(const float4*)&As[k][ty * 8 + 4];
      float4 bv = *(const float4*)&Bs[k][tx * 4];
      float a[8] = {av0.x, av0.y, av0.z, av0.w, av1.x, av1.y, av1.z, av1.w};
      float bq[4] = {bv.x, bv.y, bv.z, bv.w};
      #pragma unroll
      for (int i = 0; i < 8; ++i)
        #pragma unroll
        for (int jj = 0; jj < 4; ++jj)
          acc[i][jj] = fmaf(a[i], bq[jj], acc[i][jj]);
    }
    __syncthreads();
  }
  int nbase = tile_n + tx * 4;
  float4 bb4 = *(const float4*)&bias[nbase];
  #pragma unroll
  for (int i = 0; i < 8; ++i) {
    int m = tile_m + ty * 8 + i;
    int s_local = m >> 5, b = m & 31;
    float4 o;
    o.x = acc[i][0] + bb4.x; o.y = acc[i][1] + bb4.y;
    o.z = acc[i][2] + bb4.z; o.w = acc[i][3] + bb4.w;
    *(float4*)&xg[(((size_t)dir * Tc + s_local) * BB + b) * 512 + (nbase & 511)] = o;
  }
}

// ---------------- K3: LSTM recurrence scan (f16 dot2, k-quarter split) ----------------
// 512 threads: wave w, lane l: r = w*16 + (l&15), q = l>>4.
// Thread computes partial i,f,g,o for row r over k in [32q, 32q+32) via v_dot2_f32_f16.
// amdgpu_waves_per_eu(1,2): cap occupancy at 2 waves/SIMD -> 256-VGPR budget so
// the 64-VGPR weight array stays register-resident (the allocator's default
// 8-wave target = 64 VGPRs was spilling it to scratch -> L2 reload every step).
template<int L>
__global__ __attribute__((amdgpu_flat_work_group_size(512, 512)))
__attribute__((amdgpu_waves_per_eu(1, 2))) void scan_seg(
    const float* __restrict__ xg,   // [2][Tc][B][512] f32
    const float* __restrict__ Whh,  // [2][512][128] f32
    float* __restrict__ hout,
    float* __restrict__ hstate,     // [2][B][128]
    float* __restrict__ cstate,     // [2][B][128]
    int Tc, int p)
{
  int b = blockIdx.x & 31;
  int dir = blockIdx.x >> 5;
  int tid = threadIdx.x;
  int w = tid >> 6;
  int lane = tid & 63;
  int r = w * 16 + (lane & 15);
  int q = lane >> 4;
  bool q0 = (q == 0);
  const float* xgd = xg + (size_t)dir * Tc * BB * 512;

  // weights: 4 gate-rows (r + 128g), k-slice [32q,32q+32), packed half2 in float
  float Wf[4][16];
  #pragma unroll
  for (int g = 0; g < 4; ++g) {
    const float4* wr = (const float4*)(Whh + ((size_t)dir * 512 + g * 128 + r) * 128 + q * 32);
    #pragma unroll
    for (int e2 = 0; e2 < 8; ++e2) {
      float4 v = wr[e2];
      half2_t lo, hi;
      lo.x = (_Float16)v.x; lo.y = (_Float16)v.y;
      hi.x = (_Float16)v.z; hi.y = (_Float16)v.w;
      Wf[g][2 * e2] = h22f(lo); Wf[g][2 * e2 + 1] = h22f(hi);
    }
  }
  // pin into arch VGPRs (one-time, outside the step loop)
  #pragma unroll
  for (int g = 0; g < 4; ++g)
    #pragma unroll
    for (int e = 0; e < 16; ++e)
      asm volatile("" : "+v"(Wf[g][e]));

  __shared__ alignas(16) _Float16 hl[2][128];
  int sidx = (dir * 32 + b) * 128 + r;
  float c = cstate[sidx];
  if (q0) hl[0][r] = (_Float16)hstate[sidx];
  __syncthreads();

  int tbase = dir ? (SS - 1 - p * Tc) : p * Tc;
  int dt = dir ? -1 : 1;

  // depth-2 prefetch ring of gate preactivations (q0 lanes only)
  float x0g[4] = {0.f, 0.f, 0.f, 0.f}, x1g[4] = {0.f, 0.f, 0.f, 0.f};
  if (q0) {
    #pragma unroll
    for (int g = 0; g < 4; ++g) x0g[g] = xgd[(size_t)b * 512 + g * 128 + r];
    if (Tc > 1) {
      #pragma unroll
      for (int g = 0; g < 4; ++g) x1g[g] = xgd[((size_t)BB + b) * 512 + g * 128 + r];
    }
  }

  int cur = 0;
  for (int s = 0; s < Tc; ++s) {
    float x2g[4] = {0.f, 0.f, 0.f, 0.f};
    if (q0 && s + 2 < Tc) {
      #pragma unroll
      for (int g = 0; g < 4; ++g)
        x2g[g] = xgd[((size_t)(s + 2) * BB + b) * 512 + g * 128 + r];
    }
    float acc0 = x0g[0], acc1 = x0g[1], acc2 = x0g[2], acc3 = x0g[3];
    const float4* h4 = (const float4*)&hl[cur][q * 32];   // 4 x 16B = 32 f16
    #pragma unroll
    for (int e = 0; e < 4; ++e) {
      float4 hv = h4[e];
      half2_t p0 = f2h2(hv.x), p1 = f2h2(hv.y), p2 = f2h2(hv.z), p3 = f2h2(hv.w);
      acc0 = DOT2(p0, f2h2(Wf[0][4 * e + 0]), acc0);
      acc0 = DOT2(p1, f2h2(Wf[0][4 * e + 1]), acc0);
      acc0 = DOT2(p2, f2h2(Wf[0][4 * e + 2]), acc0);
      acc0 = DOT2(p3, f2h2(Wf[0][4 * e + 3]), acc0);
      acc1 = DOT2(p0, f2h2(Wf[1][4 * e + 0]), acc1);
      acc1 = DOT2(p1, f2h2(Wf[1][4 * e + 1]), acc1);
      acc1 = DOT2(p2, f2h2(Wf[1][4 * e + 2]), acc1);
      acc1 = DOT2(p3, f2h2(Wf[1][4 * e + 3]), acc1);
      acc2 = DOT2(p0, f2h2(Wf[2][4 * e + 0]), acc2);
      acc2 = DOT2(p1, f2h2(Wf[2][4 * e + 1]), acc2);
      acc2 = DOT2(p2, f2h2(Wf[2][4 * e + 2]), acc2);
      acc2 = DOT2(p3, f2h2(Wf[2][4 * e + 3]), acc2);
      acc3 = DOT2(p0, f2h2(Wf[3][4 * e + 0]), acc3);
      acc3 = DOT2(p1, f2h2(Wf[3][4 * e + 1]), acc3);
      acc3 = DOT2(p2, f2h2(Wf[3][4 * e + 2]), acc3);
      acc3 = DOT2(p3, f2h2(Wf[3][4 * e + 3]), acc3);
    }
    // reduce partials across q (lane bits 4,5)
    acc0 += __shfl_xor(acc0, 16); acc0 += __shfl_xor(acc0, 32);
    acc1 += __shfl_xor(acc1, 16); acc1 += __shfl_xor(acc1, 32);
    acc2 += __shfl_xor(acc2, 16); acc2 += __shfl_xor(acc2, 32);
    acc3 += __shfl_xor(acc3, 16); acc3 += __shfl_xor(acc3, 32);
    // activation (redundant across q, deterministic)
    c = fsig(acc1) * c + fsig(acc0) * ftanh(acc2);
    float h = fsig(acc3) * ftanh(c);
    int nxt = cur ^ 1;
    if (q0) {
      hl[nxt][r] = (_Float16)h;
      if constexpr (L == 0) {
        int t = tbase + dt * s;
        hout[((size_t)t * BB + b) * 256 + (dir << 7) + r] = h;
      } else {
        hout[(((size_t)dir * Tc + s) * BB + b) * 128 + r] = h;
      }
    }
    __syncthreads();
    cur = nxt;
    x0g[0] = x1g[0]; x0g[1] = x1g[1]; x0g[2] = x1g[2]; x0g[3] = x1g[3];
    x1g[0] = x2g[0]; x1g[1] = x2g[1]; x1g[2] = x2g[2]; x1g[3] = x2g[3];
  }
  if (q0) { hstate[sidx] = (float)hl[cur][r]; cstate[sidx] = c; }
}

// ---------------- K4: partial emissions from layer-1 h chunk ----------------
__global__ __launch_bounds__(256) void emis_seg(
    const float* __restrict__ h1c, const float* __restrict__ Wtag,
    float* __restrict__ em_part, int Tc, int p)
{
  int wv = blockIdx.x * 4 + (threadIdx.x >> 6);   // over (dir, s, b)
  int lane = threadIdx.x & 63;
  int b = wv & 31;
  int rest = wv >> 5;
  int dir = (rest >= Tc) ? 1 : 0;
  int s = rest - dir * Tc;
  float2 hv = ((const float2*)(h1c + (((size_t)dir * Tc + s) * BB + b) * 128))[lane];
  float pv[3];
  #pragma unroll
  for (int tg = 0; tg < 3; ++tg) {
    float2 wvv = ((const float2*)(Wtag + tg * 256 + dir * 128))[lane];
    pv[tg] = hv.x * wvv.x + hv.y * wvv.y;
  }
  #pragma unroll
  for (int off = 32; off > 0; off >>= 1) {
    pv[0] += __shfl_xor(pv[0], off);
    pv[1] += __shfl_xor(pv[1], off);
    pv[2] += __shfl_xor(pv[2], off);
  }
  if (lane == 0) {
    int t = dir ? (SS - 1 - p * Tc - s) : (p * Tc + s);
    size_t base = ((size_t)dir * SBTOK + (size_t)t * BB + b) * 3;
    em_part[base + 0] = pv[0];
    em_part[base + 1] = pv[1];
    em_part[base + 2] = pv[2];
  }
}

// ---------------- K5a: CRF chunk transfer matrices ----------------
__global__ __launch_bounds__(256) void crf_seg(
    const float* __restrict__ ef, const float* __restrict__ eb,
    const float* __restrict__ btag, const float* __restrict__ masks,
    const float* __restrict__ dummy, const float* __restrict__ tr_,
    float* __restrict__ segM)
{
  int b = blockIdx.x;
  int tid = threadIdx.x;
  int ch = tid >> 4;
  int lane = tid & 63;
  int jj = tid & 15;
  int base = lane & 48;
  int col = (jj < 3) ? jj : 0;
  float T0 = tr_[0 * 3 + col], T1 = tr_[1 * 3 + col], T2 = tr_[2 * 3 + col];
  float btj = btag[col];
  const int* mk = (const int*)masks + (size_t)b * SS;
  int t0 = 1 + ch * 128;
  int len = (ch == 15) ? 127 : 128;
  float S0, S1, S2;
  {
    size_t eo = ((size_t)t0 * BB + b) * 3;
    float e = ef[eo + col] + eb[eo + col] + btj;
    if (mk[t0] != 0) { S0 = T0 + e; S1 = T1 + e; S2 = T2 + e; }
    else { S0 = (col == 0) ? 0.f : NEG; S1 = (col == 1) ? 0.f : NEG; S2 = (col == 2) ? 0.f : NEG; }
  }
  for (int i = 1; i < len; ++i) {
    int t = t0 + i;
    size_t eo = ((size_t)t * BB + b) * 3;
    float e = ef[eo + col] + eb[eo + col] + btj;
    int m = mk[t];
    float M0 = T0 + e, M1 = T1 + e, M2 = T2 + e;
    float r00 = __shfl(S0, base + 0), r01 = __shfl(S0, base + 1), r02 = __shfl(S0, base + 2);
    float r10 = __shfl(S1, base + 0), r11 = __shfl(S1, base + 1), r12 = __shfl(S1, base + 2);
    float r20 = __shfl(S2, base + 0), r21 = __shfl(S2, base + 1), r22 = __shfl(S2, base + 2);
    if (m != 0) {
      S0 = lse3(r00 + M0, r01 + M1, r02 + M2);
      S1 = lse3(r10 + M0, r11 + M1, r12 + M2);
      S2 = lse3(r20 + M0, r21 + M1, r22 + M2);
    }
  }
  if (jj < 3) {
    float* o = segM + ((size_t)b * 16 + ch) * 9;
    o[0 * 3 + jj] = S0;
    o[1 * 3 + jj] = S1;
    o[2 * 3 + jj] = S2;
  }
}

// ---------------- K5b: gold path score (parallel over t) ----------------
__global__ __launch_bounds__(64) void crf_num(
    const float* __restrict__ ef, const float* __restrict__ eb,
    const float* __restrict__ btag, const int* __restrict__ tags,
    const int* __restrict__ masks, const float* __restrict__ st,
    const float* __restrict__ et, const float* __restrict__ tr_,
    float* __restrict__ numb)
{
  int b = blockIdx.x;
  int lane = threadIdx.x;
  float T[9];
  #pragma unroll
  for (int i = 0; i < 9; ++i) T[i] = tr_[i];
  float b0 = btag[0], b1 = btag[1], b2 = btag[2];
  const int* tg = tags + (size_t)b * SS;
  const int* mk = masks + (size_t)b * SS;
  float part = 0.f;
  int cnt = 0;
  for (int t = lane; t < SS; t += 64) {
    int m = mk[t];
    cnt += (m != 0);
    if (t > 0 && m != 0) {
      int ct = tg[t], pv = tg[t - 1];
      size_t eo = ((size_t)t * BB + b) * 3;
      float bc = (ct == 0) ? b0 : ((ct == 1) ? b1 : b2);
      part += T[pv * 3 + ct] + ef[eo + ct] + eb[eo + ct] + bc;
    }
  }
  #pragma unroll
  for (int off = 32; off > 0; off >>= 1) {
    part += __shfl_xor(part, off);
    cnt += __shfl_xor(cnt, off);
  }
  if (lane == 0) {
    int tg0 = tg[0];
    float bc = (tg0 == 0) ? b0 : ((tg0 == 1) ? b1 : b2);
    float num = part + st[tg0] + ef[b * 3 + tg0] + eb[b * 3 + tg0] + bc;
    int last = tg[cnt - 1];
    num += et[last];
    numb[b] = num;
  }
}

// ---------------- K5c: combine chunks, partition, final NLL ----------------
__global__ __launch_bounds__(512) void crf_fin(
    const float* __restrict__ segM, const float* __restrict__ numb,
    const float* __restrict__ ef, const float* __restrict__ eb,
    const float* __restrict__ btag, const float* __restrict__ st,
    const float* __restrict__ et, float* __restrict__ out)
{
  int tid = threadIdx.x;
  int b = tid >> 4;
  int lane = tid & 63;
  int jj = tid & 15;
  int base = lane & 48;
  int col = (jj < 3) ? jj : 0;
  const float* sm = segM + (size_t)b * 16 * 9;
  float S0 = sm[0 * 3 + col], S1 = sm[1 * 3 + col], S2 = sm[2 * 3 + col];
  for (int ch = 1; ch < 16; ++ch) {
    float M0 = sm[ch * 9 + 0 * 3 + col];
    float M1 = sm[ch * 9 + 1 * 3 + col];
    float M2 = sm[ch * 9 + 2 * 3 + col];
    float r00 = __shfl(S0, base + 0), r01 = __shfl(S0, base + 1), r02 = __shfl(S0, base + 2);
    float r10 = __shfl(S1, base + 0), r11 = __shfl(S1, base + 1), r12 = __shfl(S1, base + 2);
    float r20 = __shfl(S2, base + 0), r21 = __shfl(S2, base + 1), r22 = __shfl(S2, base + 2);
    S0 = lse3(r00 + M0, r01 + M1, r02 + M2);
    S1 = lse3(r10 + M0, r11 + M1, r12 + M2);
    S2 = lse3(r20 + M0, r21 + M1, r22 + M2);
  }
  float A0 = st[0] + ef[b * 3 + 0] + eb[b * 3 + 0] + btag[0];
  float A1 = st[1] + ef[b * 3 + 1] + eb[b * 3 + 1] + btag[1];
  float A2 = st[2] + ef[b * 3 + 2] + eb[b * 3 + 2] + btag[2];
  float alpha = lse3(A0 + S0, A1 + S1, A2 + S2);   // column jj
  float v = alpha + et[col];
  float v0 = __shfl(v, base + 0), v1 = __shfl(v, base + 1), v2 = __shfl(v, base + 2);
  float den = lse3(v0, v1, v2);
  __shared__ float rbuf[32];
  if (jj == 0) rbuf[b] = numb[b] - den;
  __syncthreads();
  if (tid == 0) {
    float s = 0.f;
    #pragma unroll
    for (int i = 0; i < 32; ++i) s += rbuf[i];
    out[0] = -s;
  }
}

extern "C" void kernel_launch(void* const* d_in, const int* in_sizes, int n_in,
                              void* d_out, int out_size, void* d_ws, size_t ws_size,
                              hipStream_t stream) {
  const int* seq    = (const int*)d_in[0];
  const int* tags   = (const int*)d_in[1];
  const int* masks  = (const int*)d_in[2];
  const float* wemb = (const float*)d_in[3];
  const float* cemb = (const float*)d_in[4];
  const float* cWih = (const float*)d_in[5];
  const float* cb   = (const float*)d_in[6];
  const float* l0Wih = (const float*)d_in[7];
  const float* l0Whh = (const float*)d_in[8];
  const float* l0b   = (const float*)d_in[9];
  const float* l1Wih = (const float*)d_in[10];
  const float* l1Whh = (const float*)d_in[11];
  const float* l1b   = (const float*)d_in[12];
  const float* Wtag  = (const float*)d_in[13];
  const float* btag  = (const float*)d_in[14];
  const float* st    = (const float*)d_in[15];
  const float* et    = (const float*)d_in[16];
  const float* tr    = (const float*)d_in[17];
  float* outp = (float*)d_out;

  // ---- choose time-chunk Tc so the workspace fits ws_size ----
  const size_t fixed_fl = 4194304ull + 16777216ull + 393216ull + 16384ull + 8192ull;
  int Tc = 64;
  const int cands[6] = {2048, 1024, 512, 256, 128, 64};
  for (int i = 0; i < 6; ++i) {
    size_t need = (fixed_fl + (size_t)cands[i] * 40960ull) * 4ull;
    if (need <= ws_size || i == 5) { Tc = cands[i]; if (need <= ws_size) break; }
  }
  int nphase = SS / Tc;

  float* ws = (float*)d_ws;
  float* char_feat = ws;                              // 4,194,304
  float* xg      = char_feat + 4194304;               // Tc*32768
  float* h0      = xg + (size_t)Tc * 32768;           // 16,777,216
  float* h1c     = h0 + 16777216;                     // Tc*8192
  float* em_part = h1c + (size_t)Tc * 8192;           // 393,216
  float* hstate  = em_part + 393216;                  // 8,192
  float* cstate  = hstate + 8192;                     // 8,192
  float* segM    = cstate + 8192;                     // 4,608
  float* numb    = segM + 4608;                       // 32

  char_kernel<<<SBTOK * 64 / 256, 256, 0, stream>>>(seq, cemb, cWih, cb, char_feat);

  dim3 pg(Tc / 4, 16);
  // ---- layer 0 ----
  zero_kernel<<<64, 256, 0, stream>>>(hstate, 16384);
  for (int p = 0; p < nphase; ++p) {
    proj_seg<0, 192><<<pg, 256, 0, stream>>>(char_feat, seq, wemb, l0Wih, l0b, xg, Tc, p);
    scan_seg<0><<<64, 512, 0, stream>>>(xg, l0Whh, h0, hstate, cstate, Tc, p);
  }
  // ---- layer 1 ----
  zero_kernel<<<64, 256, 0, stream>>>(hstate, 16384);
  for (int p = 0; p < nphase; ++p) {
    proj_seg<1, 256><<<pg, 256, 0, stream>>>(h0, seq, wemb, l1Wih, l1b, xg, Tc, p);
    scan_seg<1><<<64, 512, 0, stream>>>(xg, l1Whh, h1c, hstate, cstate, Tc, p);
    emis_seg<<<Tc * 16, 256, 0, stream>>>(h1c, Wtag, em_part, Tc, p);
  }
  const float* ef = em_part;
  const float* eb = em_part + (size_t)SBTOK * 3;
  crf_seg<<<32, 256, 0, stream>>>(ef, eb, btag, (const float*)masks, nullptr, tr, segM);
  crf_num<<<32, 64, 0, stream>>>(ef, eb, btag, tags, masks, st, et, tr, numb);
  crf_fin<<<1, 512, 0, stream>>>(segM, numb, ef, eb, btag, st, et, outp);
}

// Round 12
// 4580.575 us; speedup vs baseline: 1.5587x; 1.1245x over previous
//
#include <hip/hip_runtime.h>
#include <hip/hip_bf16.h>
#include <math.h>

#define SS 2048
#define BB 32
#define SBTOK (SS * BB)   // 65536 tokens
#define NEG (-1e30f)

typedef _Float16 half2_t __attribute__((ext_vector_type(2)));
typedef _Float16 half8_t __attribute__((ext_vector_type(8)));
typedef float f32x4_t __attribute__((ext_vector_type(4)));

#if __has_builtin(__builtin_amdgcn_fdot2)
#define DOT2(a, b, c) __builtin_amdgcn_fdot2((a), (b), (c), false)
#else
#define DOT2(a, b, c) fmaf((float)(a).x, (float)(b).x, fmaf((float)(a).y, (float)(b).y, (c)))
#endif

#if __has_builtin(__builtin_amdgcn_rcpf)
#define FRCP(x) __builtin_amdgcn_rcpf(x)
#else
#define FRCP(x) (1.f / (x))
#endif

__device__ __forceinline__ half2_t f2h2(float f) {
  union { float f; half2_t h; } u; u.f = f; return u.h;
}
__device__ __forceinline__ float h22f(half2_t h) {
  union { half2_t h; float f; } u; u.h = h; return u.f;
}

// fast sigmoid / tanh (v_rcp based, ~1 ulp rcp; plenty for 2% tolerance)
__device__ __forceinline__ float fsig(float x) {
  float e = __expf(-x);
  return FRCP(1.f + e);
}
__device__ __forceinline__ float ftanh(float x) {
  float e = __expf(-2.f * fabsf(x));           // in (0,1]
  float r = 1.f - (e + e) * FRCP(1.f + e);     // tanh(|x|)
  return copysignf(r, x);
}
__device__ __forceinline__ float lse3(float x, float y, float z) {
  float mx = fmaxf(fmaxf(x, y), z);
  return mx + __logf(__expf(x - mx) + __expf(y - mx) + __expf(z - mx));
}

// ---------------- K0: zero scratch (state buffers) ----------------
__global__ __launch_bounds__(256) void zero_kernel(float* __restrict__ p, int n) {
  int i = blockIdx.x * 256 + threadIdx.x;
  if (i < n) p[i] = 0.f;
}

// ---------------- K1: char-LSTM features (1 step, h0=c0=0) ----------------
__global__ __launch_bounds__(256) void char_kernel(
    const int* __restrict__ seq, const float* __restrict__ cemb,
    const float* __restrict__ cWih, const float* __restrict__ cb,
    float* __restrict__ char_feat)
{
  int gid = blockIdx.x * 256 + threadIdx.x;
  int token = gid >> 6;          // t*B + b
  int u = gid & 63;
  int dir = u >> 5;
  int j = u & 31;
  int t = token >> 5;            // B = 32
  int b = token & 31;
  int sv = seq[b * SS + t] & 255;
  const float* ce = cemb + sv * 32;
  const float* Wd = cWih + dir * (128 * 32);
  float ai = cb[dir * 128 + j];
  float ag = cb[dir * 128 + 64 + j];
  float ao = cb[dir * 128 + 96 + j];
  #pragma unroll
  for (int k = 0; k < 32; ++k) {
    float cv = ce[k];
    ai = fmaf(cv, Wd[j * 32 + k], ai);
    ag = fmaf(cv, Wd[(64 + j) * 32 + k], ag);
    ao = fmaf(cv, Wd[(96 + j) * 32 + k], ao);
  }
  float c = fsig(ai) * ftanh(ag);
  float h = fsig(ao) * ftanh(c);
  char_feat[(size_t)token * 64 + dir * 32 + j] = h;
}

// ---------------- K2: input projection via MFMA (f16 in, f32 accum) ----------------
// Tile: 64 tokens x 256 gates per WG; 4 waves, wave w owns gates [tile_n+w*64, +64).
// Fragment maps HW-verified in round 10 (absmax 0.0):
//   A: row = lane&15, k = (lane>>4)*8 + j ;  B: same with row = gate
//   D: col(lane&15) = gate, row = (lane>>4)*4 + reg = token
// LDS rows padded to 40 halves: 80B stride -> 2-way bank conflict (free), 16B aligned.
template<int MODE, int D>
__global__ __launch_bounds__(256, 1) void proj_mfma(
    const float* __restrict__ Asrc, const int* __restrict__ seq,
    const float* __restrict__ wemb, const float* __restrict__ W,
    const float* __restrict__ bias, float* __restrict__ xg,
    int Tc, int p)
{
  __shared__ alignas(16) _Float16 Al[64 * 40];    // [m][k]
  __shared__ alignas(16) _Float16 Bl[256 * 40];   // [n][k]
  int tid = threadIdx.x;
  int tile_m = blockIdx.x * 64;    // token-local rows
  int tile_n = blockIdx.y * 256;   // gates; dir = tile_n>=512
  int dir = tile_n >> 9;
  int w = tid >> 6, l = tid & 63;
  int ma = l & 15;
  int kg = l >> 4;

  f32x4_t acc[4][4];
  #pragma unroll
  for (int mt = 0; mt < 4; ++mt)
    #pragma unroll
    for (int nt = 0; nt < 4; ++nt)
      acc[mt][nt] = (f32x4_t){0.f, 0.f, 0.f, 0.f};

  for (int k0 = 0; k0 < D; k0 += 32) {
    // stage A: 64 x 32 (8 elems/thread, coalesced 32-wide rows)
    #pragma unroll
    for (int i = tid; i < 2048; i += 256) {
      int m = i >> 5, k = i & 31;
      int token = tile_m + m;
      int s_local = token >> 5, b = token & 31;
      int t = dir ? (SS - 1 - p * Tc - s_local) : (p * Tc + s_local);
      int d = k0 + k;
      float av;
      if constexpr (MODE == 0) {
        if (d < 128) {
          int sv = seq[b * SS + t] & 255;
          av = wemb[sv * 128 + d];
        } else {
          av = Asrc[(size_t)(t * BB + b) * 64 + (d - 128)];
        }
      } else {
        av = Asrc[(size_t)(t * BB + b) * 256 + d];
      }
      Al[m * 40 + k] = (_Float16)av;
    }
    // stage B: 256 x 32 (32 elems/thread)
    #pragma unroll
    for (int i = tid; i < 8192; i += 256) {
      int n = i >> 5, k = i & 31;
      Bl[n * 40 + k] = (_Float16)W[(size_t)(tile_n + n) * D + (k0 + k)];
    }
    __syncthreads();
    half8_t af[4], bf[4];
    #pragma unroll
    for (int mt = 0; mt < 4; ++mt)
      af[mt] = *(const half8_t*)&Al[(mt * 16 + ma) * 40 + kg * 8];
    #pragma unroll
    for (int nt = 0; nt < 4; ++nt)
      bf[nt] = *(const half8_t*)&Bl[(w * 64 + nt * 16 + ma) * 40 + kg * 8];
    #pragma unroll
    for (int mt = 0; mt < 4; ++mt)
      #pragma unroll
      for (int nt = 0; nt < 4; ++nt)
        acc[mt][nt] = __builtin_amdgcn_mfma_f32_16x16x32_f16(af[mt], bf[nt], acc[mt][nt], 0, 0, 0);
    __syncthreads();
  }
  // epilogue
  #pragma unroll
  for (int nt = 0; nt < 4; ++nt) {
    int n = tile_n + w * 64 + nt * 16 + ma;
    float bb = bias[n];
    #pragma unroll
    for (int mt = 0; mt < 4; ++mt) {
      #pragma unroll
      for (int reg = 0; reg < 4; ++reg) {
        int token = tile_m + mt * 16 + (l >> 4) * 4 + reg;
        int s_local = token >> 5, b = token & 31;
        xg[(((size_t)dir * Tc + s_local) * BB + b) * 512 + (n & 511)] = acc[mt][nt][reg] + bb;
      }
    }
  }
}

// ---------------- K3: LSTM recurrence scan (f16 dot2, k-quarter split) ----------------
// unchanged from round 11
template<int L>
__global__ __attribute__((amdgpu_flat_work_group_size(512, 512)))
__attribute__((amdgpu_waves_per_eu(1, 2))) void scan_seg(
    const float* __restrict__ xg,   // [2][Tc][B][512] f32
    const float* __restrict__ Whh,  // [2][512][128] f32
    float* __restrict__ hout,
    float* __restrict__ hstate,     // [2][B][128]
    float* __restrict__ cstate,     // [2][B][128]
    int Tc, int p)
{
  int b = blockIdx.x & 31;
  int dir = blockIdx.x >> 5;
  int tid = threadIdx.x;
  int w = tid >> 6;
  int lane = tid & 63;
  int r = w * 16 + (lane & 15);
  int q = lane >> 4;
  bool q0 = (q == 0);
  const float* xgd = xg + (size_t)dir * Tc * BB * 512;

  float Wf[4][16];
  #pragma unroll
  for (int g = 0; g < 4; ++g) {
    const float4* wr = (const float4*)(Whh + ((size_t)dir * 512 + g * 128 + r) * 128 + q * 32);
    #pragma unroll
    for (int e2 = 0; e2 < 8; ++e2) {
      float4 v = wr[e2];
      half2_t lo, hi;
      lo.x = (_Float16)v.x; lo.y = (_Float16)v.y;
      hi.x = (_Float16)v.z; hi.y = (_Float16)v.w;
      Wf[g][2 * e2] = h22f(lo); Wf[g][2 * e2 + 1] = h22f(hi);
    }
  }
  #pragma unroll
  for (int g = 0; g < 4; ++g)
    #pragma unroll
    for (int e = 0; e < 16; ++e)
      asm volatile("" : "+v"(Wf[g][e]));

  __shared__ alignas(16) _Float16 hl[2][128];
  int sidx = (dir * 32 + b) * 128 + r;
  float c = cstate[sidx];
  if (q0) hl[0][r] = (_Float16)hstate[sidx];
  __syncthreads();

  int tbase = dir ? (SS - 1 - p * Tc) : p * Tc;
  int dt = dir ? -1 : 1;

  float x0g[4] = {0.f, 0.f, 0.f, 0.f}, x1g[4] = {0.f, 0.f, 0.f, 0.f};
  if (q0) {
    #pragma unroll
    for (int g = 0; g < 4; ++g) x0g[g] = xgd[(size_t)b * 512 + g * 128 + r];
    if (Tc > 1) {
      #pragma unroll
      for (int g = 0; g < 4; ++g) x1g[g] = xgd[((size_t)BB + b) * 512 + g * 128 + r];
    }
  }

  int cur = 0;
  for (int s = 0; s < Tc; ++s) {
    float x2g[4] = {0.f, 0.f, 0.f, 0.f};
    if (q0 && s + 2 < Tc) {
      #pragma unroll
      for (int g = 0; g < 4; ++g)
        x2g[g] = xgd[((size_t)(s + 2) * BB + b) * 512 + g * 128 + r];
    }
    float acc0 = x0g[0], acc1 = x0g[1], acc2 = x0g[2], acc3 = x0g[3];
    const float4* h4 = (const float4*)&hl[cur][q * 32];   // 4 x 16B = 32 f16
    #pragma unroll
    for (int e = 0; e < 4; ++e) {
      float4 hv = h4[e];
      half2_t p0 = f2h2(hv.x), p1 = f2h2(hv.y), p2 = f2h2(hv.z), p3 = f2h2(hv.w);
      acc0 = DOT2(p0, f2h2(Wf[0][4 * e + 0]), acc0);
      acc0 = DOT2(p1, f2h2(Wf[0][4 * e + 1]), acc0);
      acc0 = DOT2(p2, f2h2(Wf[0][4 * e + 2]), acc0);
      acc0 = DOT2(p3, f2h2(Wf[0][4 * e + 3]), acc0);
      acc1 = DOT2(p0, f2h2(Wf[1][4 * e + 0]), acc1);
      acc1 = DOT2(p1, f2h2(Wf[1][4 * e + 1]), acc1);
      acc1 = DOT2(p2, f2h2(Wf[1][4 * e + 2]), acc1);
      acc1 = DOT2(p3, f2h2(Wf[1][4 * e + 3]), acc1);
      acc2 = DOT2(p0, f2h2(Wf[2][4 * e + 0]), acc2);
      acc2 = DOT2(p1, f2h2(Wf[2][4 * e + 1]), acc2);
      acc2 = DOT2(p2, f2h2(Wf[2][4 * e + 2]), acc2);
      acc2 = DOT2(p3, f2h2(Wf[2][4 * e + 3]), acc2);
      acc3 = DOT2(p0, f2h2(Wf[3][4 * e + 0]), acc3);
      acc3 = DOT2(p1, f2h2(Wf[3][4 * e + 1]), acc3);
      acc3 = DOT2(p2, f2h2(Wf[3][4 * e + 2]), acc3);
      acc3 = DOT2(p3, f2h2(Wf[3][4 * e + 3]), acc3);
    }
    acc0 += __shfl_xor(acc0, 16); acc0 += __shfl_xor(acc0, 32);
    acc1 += __shfl_xor(acc1, 16); acc1 += __shfl_xor(acc1, 32);
    acc2 += __shfl_xor(acc2, 16); acc2 += __shfl_xor(acc2, 32);
    acc3 += __shfl_xor(acc3, 16); acc3 += __shfl_xor(acc3, 32);
    c = fsig(acc1) * c + fsig(acc0) * ftanh(acc2);
    float h = fsig(acc3) * ftanh(c);
    int nxt = cur ^ 1;
    if (q0) {
      hl[nxt][r] = (_Float16)h;
      if constexpr (L == 0) {
        int t = tbase + dt * s;
        hout[((size_t)t * BB + b) * 256 + (dir << 7) + r] = h;
      } else {
        hout[(((size_t)dir * Tc + s) * BB + b) * 128 + r] = h;
      }
    }
    __syncthreads();
    cur = nxt;
    x0g[0] = x1g[0]; x0g[1] = x1g[1]; x0g[2] = x1g[2]; x0g[3] = x1g[3];
    x1g[0] = x2g[0]; x1g[1] = x2g[1]; x1g[2] = x2g[2]; x1g[3] = x2g[3];
  }
  if (q0) { hstate[sidx] = (float)hl[cur][r]; cstate[sidx] = c; }
}

// ---------------- K4: partial emissions from layer-1 h chunk ----------------
__global__ __launch_bounds__(256) void emis_seg(
    const float* __restrict__ h1c, const float* __restrict__ Wtag,
    float* __restrict__ em_part, int Tc, int p)
{
  int wv = blockIdx.x * 4 + (threadIdx.x >> 6);   // over (dir, s, b)
  int lane = threadIdx.x & 63;
  int b = wv & 31;
  int rest = wv >> 5;
  int dir = (rest >= Tc) ? 1 : 0;
  int s = rest - dir * Tc;
  float2 hv = ((const float2*)(h1c + (((size_t)dir * Tc + s) * BB + b) * 128))[lane];
  float pv[3];
  #pragma unroll
  for (int tg = 0; tg < 3; ++tg) {
    float2 wvv = ((const float2*)(Wtag + tg * 256 + dir * 128))[lane];
    pv[tg] = hv.x * wvv.x + hv.y * wvv.y;
  }
  #pragma unroll
  for (int off = 32; off > 0; off >>= 1) {
    pv[0] += __shfl_xor(pv[0], off);
    pv[1] += __shfl_xor(pv[1], off);
    pv[2] += __shfl_xor(pv[2], off);
  }
  if (lane == 0) {
    int t = dir ? (SS - 1 - p * Tc - s) : (p * Tc + s);
    size_t base = ((size_t)dir * SBTOK + (size_t)t * BB + b) * 3;
    em_part[base + 0] = pv[0];
    em_part[base + 1] = pv[1];
    em_part[base + 2] = pv[2];
  }
}

// ---------------- K5a: CRF chunk transfer matrices ----------------
__global__ __launch_bounds__(256) void crf_seg(
    const float* __restrict__ ef, const float* __restrict__ eb,
    const float* __restrict__ btag, const float* __restrict__ masks,
    const float* __restrict__ dummy, const float* __restrict__ tr_,
    float* __restrict__ segM)
{
  int b = blockIdx.x;
  int tid = threadIdx.x;
  int ch = tid >> 4;
  int lane = tid & 63;
  int jj = tid & 15;
  int base = lane & 48;
  int col = (jj < 3) ? jj : 0;
  float T0 = tr_[0 * 3 + col], T1 = tr_[1 * 3 + col], T2 = tr_[2 * 3 + col];
  float btj = btag[col];
  const int* mk = (const int*)masks + (size_t)b * SS;
  int t0 = 1 + ch * 128;
  int len = (ch == 15) ? 127 : 128;
  float S0, S1, S2;
  {
    size_t eo = ((size_t)t0 * BB + b) * 3;
    float e = ef[eo + col] + eb[eo + col] + btj;
    if (mk[t0] != 0) { S0 = T0 + e; S1 = T1 + e; S2 = T2 + e; }
    else { S0 = (col == 0) ? 0.f : NEG; S1 = (col == 1) ? 0.f : NEG; S2 = (col == 2) ? 0.f : NEG; }
  }
  for (int i = 1; i < len; ++i) {
    int t = t0 + i;
    size_t eo = ((size_t)t * BB + b) * 3;
    float e = ef[eo + col] + eb[eo + col] + btj;
    int m = mk[t];
    float M0 = T0 + e, M1 = T1 + e, M2 = T2 + e;
    float r00 = __shfl(S0, base + 0), r01 = __shfl(S0, base + 1), r02 = __shfl(S0, base + 2);
    float r10 = __shfl(S1, base + 0), r11 = __shfl(S1, base + 1), r12 = __shfl(S1, base + 2);
    float r20 = __shfl(S2, base + 0), r21 = __shfl(S2, base + 1), r22 = __shfl(S2, base + 2);
    if (m != 0) {
      S0 = lse3(r00 + M0, r01 + M1, r02 + M2);
      S1 = lse3(r10 + M0, r11 + M1, r12 + M2);
      S2 = lse3(r20 + M0, r21 + M1, r22 + M2);
    }
  }
  if (jj < 3) {
    float* o = segM + ((size_t)b * 16 + ch) * 9;
    o[0 * 3 + jj] = S0;
    o[1 * 3 + jj] = S1;
    o[2 * 3 + jj] = S2;
  }
}

// ---------------- K5b: gold path score (parallel over t) ----------------
__global__ __launch_bounds__(64) void crf_num(
    const float* __restrict__ ef, const float* __restrict__ eb,
    const float* __restrict__ btag, const int* __restrict__ tags,
    const int* __restrict__ masks, const float* __restrict__ st,
    const float* __restrict__ et, const float* __restrict__ tr_,
    float* __restrict__ numb)
{
  int b = blockIdx.x;
  int lane = threadIdx.x;
  float T[9];
  #pragma unroll
  for (int i = 0; i < 9; ++i) T[i] = tr_[i];
  float b0 = btag[0], b1 = btag[1], b2 = btag[2];
  const int* tg = tags + (size_t)b * SS;
  const int* mk = masks + (size_t)b * SS;
  float part = 0.f;
  int cnt = 0;
  for (int t = lane; t < SS; t += 64) {
    int m = mk[t];
    cnt += (m != 0);
    if (t > 0 && m != 0) {
      int ct = tg[t], pv = tg[t - 1];
      size_t eo = ((size_t)t * BB + b) * 3;
      float bc = (ct == 0) ? b0 : ((ct == 1) ? b1 : b2);
      part += T[pv * 3 + ct] + ef[eo + ct] + eb[eo + ct] + bc;
    }
  }
  #pragma unroll
  for (int off = 32; off > 0; off >>= 1) {
    part += __shfl_xor(part, off);
    cnt += __shfl_xor(cnt, off);
  }
  if (lane == 0) {
    int tg0 = tg[0];
    float bc = (tg0 == 0) ? b0 : ((tg0 == 1) ? b1 : b2);
    float num = part + st[tg0] + ef[b * 3 + tg0] + eb[b * 3 + tg0] + bc;
    int last = tg[cnt - 1];
    num += et[last];
    numb[b] = num;
  }
}

// ---------------- K5c: combine chunks, partition, final NLL ----------------
__global__ __launch_bounds__(512) void crf_fin(
    const float* __restrict__ segM, const float* __restrict__ numb,
    const float* __restrict__ ef, const float* __restrict__ eb,
    const float* __restrict__ btag, const float* __restrict__ st,
    const float* __restrict__ et, float* __restrict__ out)
{
  int tid = threadIdx.x;
  int b = tid >> 4;
  int lane = tid & 63;
  int jj = tid & 15;
  int base = lane & 48;
  int col = (jj < 3) ? jj : 0;
  const float* sm = segM + (size_t)b * 16 * 9;
  float S0 = sm[0 * 3 + col], S1 = sm[1 * 3 + col], S2 = sm[2 * 3 + col];
  for (int ch = 1; ch < 16; ++ch) {
    float M0 = sm[ch * 9 + 0 * 3 + col];
    float M1 = sm[ch * 9 + 1 * 3 + col];
    float M2 = sm[ch * 9 + 2 * 3 + col];
    float r00 = __shfl(S0, base + 0), r01 = __shfl(S0, base + 1), r02 = __shfl(S0, base + 2);
    float r10 = __shfl(S1, base + 0), r11 = __shfl(S1, base + 1), r12 = __shfl(S1, base + 2);
    float r20 = __shfl(S2, base + 0), r21 = __shfl(S2, base + 1), r22 = __shfl(S2, base + 2);
    S0 = lse3(r00 + M0, r01 + M1, r02 + M2);
    S1 = lse3(r10 + M0, r11 + M1, r12 + M2);
    S2 = lse3(r20 + M0, r21 + M1, r22 + M2);
  }
  float A0 = st[0] + ef[b * 3 + 0] + eb[b * 3 + 0] + btag[0];
  float A1 = st[1] + ef[b * 3 + 1] + eb[b * 3 + 1] + btag[1];
  float A2 = st[2] + ef[b * 3 + 2] + eb[b * 3 + 2] + btag[2];
  float alpha = lse3(A0 + S0, A1 + S1, A2 + S2);   // column jj
  float v = alpha + et[col];
  float v0 = __shfl(v, base + 0), v1 = __shfl(v, base + 1), v2 = __shfl(v, base + 2);
  float den = lse3(v0, v1, v2);
  __shared__ float rbuf[32];
  if (jj == 0) rbuf[b] = numb[b] - den;
  __syncthreads();
  if (tid == 0) {
    float s = 0.f;
    #pragma unroll
    for (int i = 0; i < 32; ++i) s += rbuf[i];
    out[0] = -s;
  }
}

extern "C" void kernel_launch(void* const* d_in, const int* in_sizes, int n_in,
                              void* d_out, int out_size, void* d_ws, size_t ws_size,
                              hipStream_t stream) {
  const int* seq    = (const int*)d_in[0];
  const int* tags   = (const int*)d_in[1];
  const int* masks  = (const int*)d_in[2];
  const float* wemb = (const float*)d_in[3];
  const float* cemb = (const float*)d_in[4];
  const float* cWih = (const float*)d_in[5];
  const float* cb   = (const float*)d_in[6];
  const float* l0Wih = (const float*)d_in[7];
  const float* l0Whh = (const float*)d_in[8];
  const float* l0b   = (const float*)d_in[9];
  const float* l1Wih = (const float*)d_in[10];
  const float* l1Whh = (const float*)d_in[11];
  const float* l1b   = (const float*)d_in[12];
  const float* Wtag  = (const float*)d_in[13];
  const float* btag  = (const float*)d_in[14];
  const float* st    = (const float*)d_in[15];
  const float* et    = (const float*)d_in[16];
  const float* tr    = (const float*)d_in[17];
  float* outp = (float*)d_out;

  // ---- choose time-chunk Tc so the workspace fits ws_size ----
  const size_t fixed_fl = 4194304ull + 16777216ull + 393216ull + 16384ull + 8192ull;
  int Tc = 64;
  const int cands[6] = {2048, 1024, 512, 256, 128, 64};
  for (int i = 0; i < 6; ++i) {
    size_t need = (fixed_fl + (size_t)cands[i] * 40960ull) * 4ull;
    if (need <= ws_size || i == 5) { Tc = cands[i]; if (need <= ws_size) break; }
  }
  int nphase = SS / Tc;

  float* ws = (float*)d_ws;
  float* char_feat = ws;                              // 4,194,304
  float* xg      = char_feat + 4194304;               // Tc*32768
  float* h0      = xg + (size_t)Tc * 32768;           // 16,777,216
  float* h1c     = h0 + 16777216;                     // Tc*8192
  float* em_part = h1c + (size_t)Tc * 8192;           // 393,216
  float* hstate  = em_part + 393216;                  // 8,192
  float* cstate  = hstate + 8192;                     // 8,192
  float* segM    = cstate + 8192;                     // 4,608
  float* numb    = segM + 4608;                       // 32

  char_kernel<<<SBTOK * 64 / 256, 256, 0, stream>>>(seq, cemb, cWih, cb, char_feat);

  dim3 pg(Tc / 2, 4);
  // ---- layer 0 ----
  zero_kernel<<<64, 256, 0, stream>>>(hstate, 16384);
  for (int p = 0; p < nphase; ++p) {
    proj_mfma<0, 192><<<pg, 256, 0, stream>>>(char_feat, seq, wemb, l0Wih, l0b, xg, Tc, p);
    scan_seg<0><<<64, 512, 0, stream>>>(xg, l0Whh, h0, hstate, cstate, Tc, p);
  }
  // ---- layer 1 ----
  zero_kernel<<<64, 256, 0, stream>>>(hstate, 16384);
  for (int p = 0; p < nphase; ++p) {
    proj_mfma<1, 256><<<pg, 256, 0, stream>>>(h0, seq, wemb, l1Wih, l1b, xg, Tc, p);
    scan_seg<1><<<64, 512, 0, stream>>>(xg, l1Whh, h1c, hstate, cstate, Tc, p);
    emis_seg<<<Tc * 16, 256, 0, stream>>>(h1c, Wtag, em_part, Tc, p);
  }
  const float* ef = em_part;
  const float* eb = em_part + (size_t)SBTOK * 3;
  crf_seg<<<32, 256, 0, stream>>>(ef, eb, btag, (const float*)masks, nullptr, tr, segM);
  crf_num<<<32, 64, 0, stream>>>(ef, eb, btag, tags, masks, st, et, tr, numb);
  crf_fin<<<1, 512, 0, stream>>>(segM, numb, ef, eb, btag, st, et, outp);
}

// Round 13
// 3584.630 us; speedup vs baseline: 1.9917x; 1.2778x over previous
//
#include <hip/hip_runtime.h>
#include <hip/hip_bf16.h>
#include <math.h>

#define SS 2048
#define BB 32
#define SBTOK (SS * BB)   // 65536 tokens
#define NEG (-1e30f)

typedef _Float16 half8_t __attribute__((ext_vector_type(8)));
typedef float f32x4_t __attribute__((ext_vector_type(4)));

#if __has_builtin(__builtin_amdgcn_rcpf)
#define FRCP(x) __builtin_amdgcn_rcpf(x)
#else
#define FRCP(x) (1.f / (x))
#endif

// fast sigmoid / tanh (v_rcp based, ~1 ulp rcp; plenty for 2% tolerance)
__device__ __forceinline__ float fsig(float x) {
  float e = __expf(-x);
  return FRCP(1.f + e);
}
__device__ __forceinline__ float ftanh(float x) {
  float e = __expf(-2.f * fabsf(x));           // in (0,1]
  float r = 1.f - (e + e) * FRCP(1.f + e);     // tanh(|x|)
  return copysignf(r, x);
}
__device__ __forceinline__ float lse3(float x, float y, float z) {
  float mx = fmaxf(fmaxf(x, y), z);
  return mx + __logf(__expf(x - mx) + __expf(y - mx) + __expf(z - mx));
}

// ---------------- K0: zero scratch (state buffers) ----------------
__global__ __launch_bounds__(256) void zero_kernel(float* __restrict__ p, int n) {
  int i = blockIdx.x * 256 + threadIdx.x;
  if (i < n) p[i] = 0.f;
}

// ---------------- K1: char-LSTM features (1 step, h0=c0=0) ----------------
__global__ __launch_bounds__(256) void char_kernel(
    const int* __restrict__ seq, const float* __restrict__ cemb,
    const float* __restrict__ cWih, const float* __restrict__ cb,
    float* __restrict__ char_feat)
{
  int gid = blockIdx.x * 256 + threadIdx.x;
  int token = gid >> 6;          // t*B + b
  int u = gid & 63;
  int dir = u >> 5;
  int j = u & 31;
  int t = token >> 5;            // B = 32
  int b = token & 31;
  int sv = seq[b * SS + t] & 255;
  const float* ce = cemb + sv * 32;
  const float* Wd = cWih + dir * (128 * 32);
  float ai = cb[dir * 128 + j];
  float ag = cb[dir * 128 + 64 + j];
  float ao = cb[dir * 128 + 96 + j];
  #pragma unroll
  for (int k = 0; k < 32; ++k) {
    float cv = ce[k];
    ai = fmaf(cv, Wd[j * 32 + k], ai);
    ag = fmaf(cv, Wd[(64 + j) * 32 + k], ag);
    ao = fmaf(cv, Wd[(96 + j) * 32 + k], ao);
  }
  float c = fsig(ai) * ftanh(ag);
  float h = fsig(ao) * ftanh(c);
  char_feat[(size_t)token * 64 + dir * 32 + j] = h;
}

// ---------------- K2: input projection via MFMA (f16 in, f32 accum) ----------------
// unchanged from round 12 (verified: absmax 0.0, −570 µs)
template<int MODE, int D>
__global__ __launch_bounds__(256, 1) void proj_mfma(
    const float* __restrict__ Asrc, const int* __restrict__ seq,
    const float* __restrict__ wemb, const float* __restrict__ W,
    const float* __restrict__ bias, float* __restrict__ xg,
    int Tc, int p)
{
  __shared__ alignas(16) _Float16 Al[64 * 40];    // [m][k]
  __shared__ alignas(16) _Float16 Bl[256 * 40];   // [n][k]
  int tid = threadIdx.x;
  int tile_m = blockIdx.x * 64;    // token-local rows
  int tile_n = blockIdx.y * 256;   // gates; dir = tile_n>=512
  int dir = tile_n >> 9;
  int w = tid >> 6, l = tid & 63;
  int ma = l & 15;
  int kg = l >> 4;

  f32x4_t acc[4][4];
  #pragma unroll
  for (int mt = 0; mt < 4; ++mt)
    #pragma unroll
    for (int nt = 0; nt < 4; ++nt)
      acc[mt][nt] = (f32x4_t){0.f, 0.f, 0.f, 0.f};

  for (int k0 = 0; k0 < D; k0 += 32) {
    #pragma unroll
    for (int i = tid; i < 2048; i += 256) {
      int m = i >> 5, k = i & 31;
      int token = tile_m + m;
      int s_local = token >> 5, b = token & 31;
      int t = dir ? (SS - 1 - p * Tc - s_local) : (p * Tc + s_local);
      int d = k0 + k;
      float av;
      if constexpr (MODE == 0) {
        if (d < 128) {
          int sv = seq[b * SS + t] & 255;
          av = wemb[sv * 128 + d];
        } else {
          av = Asrc[(size_t)(t * BB + b) * 64 + (d - 128)];
        }
      } else {
        av = Asrc[(size_t)(t * BB + b) * 256 + d];
      }
      Al[m * 40 + k] = (_Float16)av;
    }
    #pragma unroll
    for (int i = tid; i < 8192; i += 256) {
      int n = i >> 5, k = i & 31;
      Bl[n * 40 + k] = (_Float16)W[(size_t)(tile_n + n) * D + (k0 + k)];
    }
    __syncthreads();
    half8_t af[4], bf[4];
    #pragma unroll
    for (int mt = 0; mt < 4; ++mt)
      af[mt] = *(const half8_t*)&Al[(mt * 16 + ma) * 40 + kg * 8];
    #pragma unroll
    for (int nt = 0; nt < 4; ++nt)
      bf[nt] = *(const half8_t*)&Bl[(w * 64 + nt * 16 + ma) * 40 + kg * 8];
    #pragma unroll
    for (int mt = 0; mt < 4; ++mt)
      #pragma unroll
      for (int nt = 0; nt < 4; ++nt)
        acc[mt][nt] = __builtin_amdgcn_mfma_f32_16x16x32_f16(af[mt], bf[nt], acc[mt][nt], 0, 0, 0);
    __syncthreads();
  }
  #pragma unroll
  for (int nt = 0; nt < 4; ++nt) {
    int n = tile_n + w * 64 + nt * 16 + ma;
    float bb = bias[n];
    #pragma unroll
    for (int mt = 0; mt < 4; ++mt) {
      #pragma unroll
      for (int reg = 0; reg < 4; ++reg) {
        int token = tile_m + mt * 16 + (l >> 4) * 4 + reg;
        int s_local = token >> 5, b = token & 31;
        xg[(((size_t)dir * Tc + s_local) * BB + b) * 512 + (n & 511)] = acc[mt][nt][reg] + bb;
      }
    }
  }
}

// ---------------- K3: LSTM recurrence scan (MFMA, register-resident Whh) ----------------
// One WG per (batch, dir), 512 threads = 8 waves. Wave w owns gates [w*64, w*64+64):
// Whh for those gates held as 16 half8 B-fragments in regs (AGPR-friendly: MFMA
// reads AGPR operands directly -> no v_accvgpr_read bloat, unlike the dot2 path).
// Per step: A = H (M=16, row 0 = real batch, rows 1-15 zero) from 4KB swizzled LDS;
// 16 mfma_f32_16x16x32_f16 per wave; lanes 0-15 (m=0) write G to LDS; barrier;
// tid<128 do activations + h/c update; barrier.
template<int L>
__global__ __launch_bounds__(512, 1) void scan_seg(
    const float* __restrict__ xg,   // [2][Tc][B][512] f32
    const float* __restrict__ Whh,  // [2][512][128] f32
    float* __restrict__ hout,
    float* __restrict__ hstate,     // [2][B][128]
    float* __restrict__ cstate,     // [2][B][128]
    int Tc, int p)
{
  int b = blockIdx.x & 31;
  int dir = blockIdx.x >> 5;
  int tid = threadIdx.x;
  int w = tid >> 6;
  int l = tid & 63;
  int n0 = w << 6;
  int ma = l & 15;
  int koff = (l >> 4) << 3;
  const float* xgd = xg + (size_t)dir * Tc * BB * 512;

  __shared__ alignas(16) _Float16 Hl[2048];   // [16][128], rows 1-15 zero, XOR-swizzled
  __shared__ alignas(16) _Float16 Gl[512];

  // ---- B-fragments: wave w's 64 gates, resident in regs for the whole kernel ----
  half8_t bf[4][4];   // [nt][ks]
  #pragma unroll
  for (int nt = 0; nt < 4; ++nt) {
    #pragma unroll
    for (int ks = 0; ks < 4; ++ks) {
      int n = n0 + nt * 16 + ma;
      const float* wp = Whh + ((size_t)dir * 512 + n) * 128 + ks * 32 + koff;
      float4 va = *(const float4*)wp;
      float4 vb = *(const float4*)(wp + 4);
      half8_t hv;
      hv[0] = (_Float16)va.x; hv[1] = (_Float16)va.y;
      hv[2] = (_Float16)va.z; hv[3] = (_Float16)va.w;
      hv[4] = (_Float16)vb.x; hv[5] = (_Float16)vb.y;
      hv[6] = (_Float16)vb.z; hv[7] = (_Float16)vb.w;
      bf[nt][ks] = hv;
    }
  }

  // ---- init H (row 0 = hstate, rows 1-15 = 0), swizzled ----
  for (int idx = tid; idx < 2048; idx += 512) {
    int row = idx >> 7, k = idx & 127;
    float v = (row == 0) ? hstate[((dir * 32 + b) << 7) + k] : 0.f;
    Hl[idx ^ ((row & 7) << 3)] = (_Float16)v;
  }

  int j = tid;                      // activation thread's hidden index (tid<128)
  bool act = (tid < 128);
  float c = act ? cstate[((dir * 32 + b) << 7) + j] : 0.f;
  __syncthreads();

  int tbase = dir ? (SS - 1 - p * Tc) : p * Tc;
  int dt = dir ? -1 : 1;

  // depth-2 xg prefetch ring (act threads)
  float x0g[4] = {0.f, 0.f, 0.f, 0.f}, x1g[4] = {0.f, 0.f, 0.f, 0.f};
  if (act) {
    #pragma unroll
    for (int g = 0; g < 4; ++g) x0g[g] = xgd[(size_t)b * 512 + g * 128 + j];
    if (Tc > 1) {
      #pragma unroll
      for (int g = 0; g < 4; ++g) x1g[g] = xgd[((size_t)BB + b) * 512 + g * 128 + j];
    }
  }

  for (int s = 0; s < Tc; ++s) {
    float x2g[4] = {0.f, 0.f, 0.f, 0.f};
    if (act && s + 2 < Tc) {
      #pragma unroll
      for (int g = 0; g < 4; ++g)
        x2g[g] = xgd[((size_t)(s + 2) * BB + b) * 512 + g * 128 + j];
    }

    // ---- MFMA phase: G[0..511] = H[0] . Whh^T ----
    half8_t af[4];
    #pragma unroll
    for (int ks = 0; ks < 4; ++ks) {
      int ei = (ma << 7) + ks * 32 + koff;
      af[ks] = *(const half8_t*)&Hl[ei ^ ((ma & 7) << 3)];
    }
    #pragma unroll
    for (int nt = 0; nt < 4; ++nt) {
      f32x4_t acc = {0.f, 0.f, 0.f, 0.f};
      #pragma unroll
      for (int ks = 0; ks < 4; ++ks)
        acc = __builtin_amdgcn_mfma_f32_16x16x32_f16(af[ks], bf[nt][ks], acc, 0, 0, 0);
      if (l < 16)                    // m=0 lives in lanes 0-15, reg 0
        Gl[n0 + nt * 16 + l] = (_Float16)acc[0];
    }
    __syncthreads();                 // Gl ready

    // ---- activation phase ----
    if (act) {
      float ig = x0g[0] + (float)Gl[j];
      float fg = x0g[1] + (float)Gl[j + 128];
      float gg = x0g[2] + (float)Gl[j + 256];
      float og = x0g[3] + (float)Gl[j + 384];
      c = fsig(fg) * c + fsig(ig) * ftanh(gg);
      float h = fsig(og) * ftanh(c);
      Hl[j] = (_Float16)h;           // row 0, swizzle = identity
      if constexpr (L == 0) {
        int t = tbase + dt * s;
        hout[((size_t)t * BB + b) * 256 + (dir << 7) + j] = h;
      } else {
        hout[(((size_t)dir * Tc + s) * BB + b) * 128 + j] = h;
      }
    }
    __syncthreads();                 // Hl ready for next step
    x0g[0] = x1g[0]; x0g[1] = x1g[1]; x0g[2] = x1g[2]; x0g[3] = x1g[3];
    x1g[0] = x2g[0]; x1g[1] = x2g[1]; x1g[2] = x2g[2]; x1g[3] = x2g[3];
  }
  if (act) {
    hstate[((dir * 32 + b) << 7) + j] = (float)Hl[j];
    cstate[((dir * 32 + b) << 7) + j] = c;
  }
}

// ---------------- K4: partial emissions from layer-1 h chunk ----------------
__global__ __launch_bounds__(256) void emis_seg(
    const float* __restrict__ h1c, const float* __restrict__ Wtag,
    float* __restrict__ em_part, int Tc, int p)
{
  int wv = blockIdx.x * 4 + (threadIdx.x >> 6);   // over (dir, s, b)
  int lane = threadIdx.x & 63;
  int b = wv & 31;
  int rest = wv >> 5;
  int dir = (rest >= Tc) ? 1 : 0;
  int s = rest - dir * Tc;
  float2 hv = ((const float2*)(h1c + (((size_t)dir * Tc + s) * BB + b) * 128))[lane];
  float pv[3];
  #pragma unroll
  for (int tg = 0; tg < 3; ++tg) {
    float2 wvv = ((const float2*)(Wtag + tg * 256 + dir * 128))[lane];
    pv[tg] = hv.x * wvv.x + hv.y * wvv.y;
  }
  #pragma unroll
  for (int off = 32; off > 0; off >>= 1) {
    pv[0] += __shfl_xor(pv[0], off);
    pv[1] += __shfl_xor(pv[1], off);
    pv[2] += __shfl_xor(pv[2], off);
  }
  if (lane == 0) {
    int t = dir ? (SS - 1 - p * Tc - s) : (p * Tc + s);
    size_t base = ((size_t)dir * SBTOK + (size_t)t * BB + b) * 3;
    em_part[base + 0] = pv[0];
    em_part[base + 1] = pv[1];
    em_part[base + 2] = pv[2];
  }
}

// ---------------- K5a: CRF chunk transfer matrices ----------------
__global__ __launch_bounds__(256) void crf_seg(
    const float* __restrict__ ef, const float* __restrict__ eb,
    const float* __restrict__ btag, const float* __restrict__ masks,
    const float* __restrict__ dummy, const float* __restrict__ tr_,
    float* __restrict__ segM)
{
  int b = blockIdx.x;
  int tid = threadIdx.x;
  int ch = tid >> 4;
  int lane = tid & 63;
  int jj = tid & 15;
  int base = lane & 48;
  int col = (jj < 3) ? jj : 0;
  float T0 = tr_[0 * 3 + col], T1 = tr_[1 * 3 + col], T2 = tr_[2 * 3 + col];
  float btj = btag[col];
  const int* mk = (const int*)masks + (size_t)b * SS;
  int t0 = 1 + ch * 128;
  int len = (ch == 15) ? 127 : 128;
  float S0, S1, S2;
  {
    size_t eo = ((size_t)t0 * BB + b) * 3;
    float e = ef[eo + col] + eb[eo + col] + btj;
    if (mk[t0] != 0) { S0 = T0 + e; S1 = T1 + e; S2 = T2 + e; }
    else { S0 = (col == 0) ? 0.f : NEG; S1 = (col == 1) ? 0.f : NEG; S2 = (col == 2) ? 0.f : NEG; }
  }
  for (int i = 1; i < len; ++i) {
    int t = t0 + i;
    size_t eo = ((size_t)t * BB + b) * 3;
    float e = ef[eo + col] + eb[eo + col] + btj;
    int m = mk[t];
    float M0 = T0 + e, M1 = T1 + e, M2 = T2 + e;
    float r00 = __shfl(S0, base + 0), r01 = __shfl(S0, base + 1), r02 = __shfl(S0, base + 2);
    float r10 = __shfl(S1, base + 0), r11 = __shfl(S1, base + 1), r12 = __shfl(S1, base + 2);
    float r20 = __shfl(S2, base + 0), r21 = __shfl(S2, base + 1), r22 = __shfl(S2, base + 2);
    if (m != 0) {
      S0 = lse3(r00 + M0, r01 + M1, r02 + M2);
      S1 = lse3(r10 + M0, r11 + M1, r12 + M2);
      S2 = lse3(r20 + M0, r21 + M1, r22 + M2);
    }
  }
  if (jj < 3) {
    float* o = segM + ((size_t)b * 16 + ch) * 9;
    o[0 * 3 + jj] = S0;
    o[1 * 3 + jj] = S1;
    o[2 * 3 + jj] = S2;
  }
}

// ---------------- K5b: gold path score (parallel over t) ----------------
__global__ __launch_bounds__(64) void crf_num(
    const float* __restrict__ ef, const float* __restrict__ eb,
    const float* __restrict__ btag, const int* __restrict__ tags,
    const int* __restrict__ masks, const float* __restrict__ st,
    const float* __restrict__ et, const float* __restrict__ tr_,
    float* __restrict__ numb)
{
  int b = blockIdx.x;
  int lane = threadIdx.x;
  float T[9];
  #pragma unroll
  for (int i = 0; i < 9; ++i) T[i] = tr_[i];
  float b0 = btag[0], b1 = btag[1], b2 = btag[2];
  const int* tg = tags + (size_t)b * SS;
  const int* mk = masks + (size_t)b * SS;
  float part = 0.f;
  int cnt = 0;
  for (int t = lane; t < SS; t += 64) {
    int m = mk[t];
    cnt += (m != 0);
    if (t > 0 && m != 0) {
      int ct = tg[t], pv = tg[t - 1];
      size_t eo = ((size_t)t * BB + b) * 3;
      float bc = (ct == 0) ? b0 : ((ct == 1) ? b1 : b2);
      part += T[pv * 3 + ct] + ef[eo + ct] + eb[eo + ct] + bc;
    }
  }
  #pragma unroll
  for (int off = 32; off > 0; off >>= 1) {
    part += __shfl_xor(part, off);
    cnt += __shfl_xor(cnt, off);
  }
  if (lane == 0) {
    int tg0 = tg[0];
    float bc = (tg0 == 0) ? b0 : ((tg0 == 1) ? b1 : b2);
    float num = part + st[tg0] + ef[b * 3 + tg0] + eb[b * 3 + tg0] + bc;
    int last = tg[cnt - 1];
    num += et[last];
    numb[b] = num;
  }
}

// ---------------- K5c: combine chunks, partition, final NLL ----------------
__global__ __launch_bounds__(512) void crf_fin(
    const float* __restrict__ segM, const float* __restrict__ numb,
    const float* __restrict__ ef, const float* __restrict__ eb,
    const float* __restrict__ btag, const float* __restrict__ st,
    const float* __restrict__ et, float* __restrict__ out)
{
  int tid = threadIdx.x;
  int b = tid >> 4;
  int lane = tid & 63;
  int jj = tid & 15;
  int base = lane & 48;
  int col = (jj < 3) ? jj : 0;
  const float* sm = segM + (size_t)b * 16 * 9;
  float S0 = sm[0 * 3 + col], S1 = sm[1 * 3 + col], S2 = sm[2 * 3 + col];
  for (int ch = 1; ch < 16; ++ch) {
    float M0 = sm[ch * 9 + 0 * 3 + col];
    float M1 = sm[ch * 9 + 1 * 3 + col];
    float M2 = sm[ch * 9 + 2 * 3 + col];
    float r00 = __shfl(S0, base + 0), r01 = __shfl(S0, base + 1), r02 = __shfl(S0, base + 2);
    float r10 = __shfl(S1, base + 0), r11 = __shfl(S1, base + 1), r12 = __shfl(S1, base + 2);
    float r20 = __shfl(S2, base + 0), r21 = __shfl(S2, base + 1), r22 = __shfl(S2, base + 2);
    S0 = lse3(r00 + M0, r01 + M1, r02 + M2);
    S1 = lse3(r10 + M0, r11 + M1, r12 + M2);
    S2 = lse3(r20 + M0, r21 + M1, r22 + M2);
  }
  float A0 = st[0] + ef[b * 3 + 0] + eb[b * 3 + 0] + btag[0];
  float A1 = st[1] + ef[b * 3 + 1] + eb[b * 3 + 1] + btag[1];
  float A2 = st[2] + ef[b * 3 + 2] + eb[b * 3 + 2] + btag[2];
  float alpha = lse3(A0 + S0, A1 + S1, A2 + S2);   // column jj
  float v = alpha + et[col];
  float v0 = __shfl(v, base + 0), v1 = __shfl(v, base + 1), v2 = __shfl(v, base + 2);
  float den = lse3(v0, v1, v2);
  __shared__ float rbuf[32];
  if (jj == 0) rbuf[b] = numb[b] - den;
  __syncthreads();
  if (tid == 0) {
    float s = 0.f;
    #pragma unroll
    for (int i = 0; i < 32; ++i) s += rbuf[i];
    out[0] = -s;
  }
}

extern "C" void kernel_launch(void* const* d_in, const int* in_sizes, int n_in,
                              void* d_out, int out_size, void* d_ws, size_t ws_size,
                              hipStream_t stream) {
  const int* seq    = (const int*)d_in[0];
  const int* tags   = (const int*)d_in[1];
  const int* masks  = (const int*)d_in[2];
  const float* wemb = (const float*)d_in[3];
  const float* cemb = (const float*)d_in[4];
  const float* cWih = (const float*)d_in[5];
  const float* cb   = (const float*)d_in[6];
  const float* l0Wih = (const float*)d_in[7];
  const float* l0Whh = (const float*)d_in[8];
  const float* l0b   = (const float*)d_in[9];
  const float* l1Wih = (const float*)d_in[10];
  const float* l1Whh = (const float*)d_in[11];
  const float* l1b   = (const float*)d_in[12];
  const float* Wtag  = (const float*)d_in[13];
  const float* btag  = (const float*)d_in[14];
  const float* st    = (const float*)d_in[15];
  const float* et    = (const float*)d_in[16];
  const float* tr    = (const float*)d_in[17];
  float* outp = (float*)d_out;

  // ---- choose time-chunk Tc so the workspace fits ws_size ----
  const size_t fixed_fl = 4194304ull + 16777216ull + 393216ull + 16384ull + 8192ull;
  int Tc = 64;
  const int cands[6] = {2048, 1024, 512, 256, 128, 64};
  for (int i = 0; i < 6; ++i) {
    size_t need = (fixed_fl + (size_t)cands[i] * 40960ull) * 4ull;
    if (need <= ws_size || i == 5) { Tc = cands[i]; if (need <= ws_size) break; }
  }
  int nphase = SS / Tc;

  float* ws = (float*)d_ws;
  float* char_feat = ws;                              // 4,194,304
  float* xg      = char_feat + 4194304;               // Tc*32768
  float* h0      = xg + (size_t)Tc * 32768;           // 16,777,216
  float* h1c     = h0 + 16777216;                     // Tc*8192
  float* em_part = h1c + (size_t)Tc * 8192;           // 393,216
  float* hstate  = em_part + 393216;                  // 8,192
  float* cstate  = hstate + 8192;                     // 8,192
  float* segM    = cstate + 8192;                     // 4,608
  float* numb    = segM + 4608;                       // 32

  char_kernel<<<SBTOK * 64 / 256, 256, 0, stream>>>(seq, cemb, cWih, cb, char_feat);

  dim3 pg(Tc / 2, 4);
  // ---- layer 0 ----
  zero_kernel<<<64, 256, 0, stream>>>(hstate, 16384);
  for (int p = 0; p < nphase; ++p) {
    proj_mfma<0, 192><<<pg, 256, 0, stream>>>(char_feat, seq, wemb, l0Wih, l0b, xg, Tc, p);
    scan_seg<0><<<64, 512, 0, stream>>>(xg, l0Whh, h0, hstate, cstate, Tc, p);
  }
  // ---- layer 1 ----
  zero_kernel<<<64, 256, 0, stream>>>(hstate, 16384);
  for (int p = 0; p < nphase; ++p) {
    proj_mfma<1, 256><<<pg, 256, 0, stream>>>(h0, seq, wemb, l1Wih, l1b, xg, Tc, p);
    scan_seg<1><<<64, 512, 0, stream>>>(xg, l1Whh, h1c, hstate, cstate, Tc, p);
    emis_seg<<<Tc * 16, 256, 0, stream>>>(h1c, Wtag, em_part, Tc, p);
  }
  const float* ef = em_part;
  const float* eb = em_part + (size_t)SBTOK * 3;
  crf_seg<<<32, 256, 0, stream>>>(ef, eb, btag, (const float*)masks, nullptr, tr, segM);
  crf_num<<<32, 64, 0, stream>>>(ef, eb, btag, tags, masks, st, et, tr, numb);
  crf_fin<<<1, 512, 0, stream>>>(segM, numb, ef, eb, btag, st, et, outp);
}